// Round 14
// baseline (177.934 us; speedup 1.0000x reference)
//
#include <hip/hip_runtime.h>

#define B_SZ   16
#define SEQ    2048
#define VOCAB  50257
#define EMBED  128
#define DSTATE 16
#define HID    256
#define NCLS   10
#define NEDGE  8192
#define KTR    64          // scan truncation: A<=0.55 -> A^64 < 2e-17
#define LN_EPS 1e-5f
#define NROW   (B_SZ*SEQ)  // 32768
#define BCAP   32          // bucket capacity per dst (Poisson lambda=4)
#define OVCAP  1024        // overflow fallback capacity

// k_prep phase block ranges
#define PB_PRECM  128                   // 256 hp, 2 per block
#define PB_CTAB   (PB_PRECM + 16)       // 16 d
#define PB_PRECB  (PB_CTAB + 1)         // +1 precB          = 145
#define PB_ZNINT  33808                 // cnt(32768)+ovf_cnt(16)+ovf(1024)
#define PB_ZBLK   34                    // ceil(33808/1024)
#define PB_ZOUT   (PB_PRECB + PB_ZBLK)  // 179: zero out[160]
#define PB_TOTAL  (PB_ZOUT + 1)         // 180

// k_ssm_fused block ranges
#define SSM_MAIN  1024                  // 16 batches x 64 tiles of 32 rows
#define SSM_PRECW (SSM_MAIN + 32)       // 1056
#define SSM_TOTAL (SSM_PRECW + 512)     // 1568 (bucket riders)

typedef float  f32x4 __attribute__((ext_vector_type(4)));
typedef short  s16x8 __attribute__((ext_vector_type(8)));

__device__ __forceinline__ float scrub(float x){
  return (x == x && fabsf(x) < 1e30f) ? x : 0.f;
}
// fp32 -> bf16 bits, round-to-nearest-even
__device__ __forceinline__ short f2b(float f){
  unsigned int u = __float_as_uint(f);
  unsigned int r = (u + 0x7fffu + ((u >> 16) & 1u)) >> 16;
  return (short)r;
}
__device__ __forceinline__ unsigned int pack2(float a, float b){
  return (unsigned int)(unsigned short)f2b(a)
       | ((unsigned int)(unsigned short)f2b(b) << 16);
}
__device__ __forceinline__ float lo2f(unsigned int v){ return __uint_as_float(v << 16); }
__device__ __forceinline__ float hi2f(unsigned int v){ return __uint_as_float(v & 0xffff0000u); }

// ---------------------------------------------------------------------------
// Prep kernel: precM + ctab + precB + workspace/out zeroing riders (r10).
// precM stays here (r12 lesson: its 32768-thread parallelism is load-bearing).
__global__ __launch_bounds__(256) void k_prep(
    const float* __restrict__ A_log, const float* __restrict__ B_w,
    const float* __restrict__ Wmsg, const float* __restrict__ Wupd,
    float* __restrict__ c_tab, short* __restrict__ Bf, float* __restrict__ MT,
    int* __restrict__ cnt, float* __restrict__ out){
  int bid = blockIdx.x, tid = threadIdx.x;
  if (bid < PB_PRECM){                           // ---- precM: 2 hp per block
    int hp = bid*2 + (tid >> 7);                 // 0..255
    int e  = tid & 127;
    const float* w2 = Wupd + (size_t)hp*384 + 128;
    float acc = 0.f;
    for (int h1 = 0; h1 < HID; ++h1)
      acc += Wmsg[h1*EMBED + e] * w2[h1];
    MT[(size_t)hp*EMBED + e] = scrub(acc);
  } else if (bid < PB_CTAB){                     // ---- ctab (wave 0 only)
    if (tid < 64){
      int d = bid - PB_PRECM, lane = tid;        // d = 0..15
      float a0 = scrub(expf(-expf(A_log[(2*lane+0)*DSTATE + d])));
      float a1 = scrub(expf(-expf(A_log[(2*lane+1)*DSTATE + d])));
      float p0 = 1.f, p1 = 1.f;
      for (int k = 0; k < KTR; ++k){
        float s = p0 + p1;
        for (int off = 32; off; off >>= 1) s += __shfl_down(s, off);
        if (lane == 0) c_tab[k*DSTATE + d] = scrub(s * (1.0f/128.0f));
        p0 *= a0; p1 *= a1;
      }
    }
  } else if (bid < PB_PRECB){                    // ---- precB (256 slots)
    int idx = tid;
    int c = idx >> 6, lane = idx & 63;
    int n = lane & 15;
    int kb = c*32 + (lane >> 4)*8;
    short v[8];
    #pragma unroll
    for (int jj = 0; jj < 8; ++jj) v[jj] = f2b(B_w[(size_t)n*EMBED + kb + jj]);
    *(s16x8*)(Bf + (size_t)idx*8) = *(s16x8*)v;
  } else if (bid < PB_ZOUT){                     // ---- zero cnt/ovf_cnt/ovf
    int idx4 = (bid-PB_PRECB)*1024 + tid*4;      // 16B-aligned int offset
    if (idx4 < PB_ZNINT){
      uint4 z; z.x = z.y = z.z = z.w = 0u;
      *(uint4*)&cnt[idx4] = z;
    }
  } else {                                       // ---- zero out[160]
    if (tid < B_SZ*NCLS) out[tid] = 0.f;
  }
}

// ---------------------------------------------------------------------------
// Fused emb-cast + bproj(MFMA) + conv + ssm + LayerNorm. (r10 exact)
__global__ __launch_bounds__(256) void k_ssm_fused(
    const int* __restrict__ tokens, const float* __restrict__ emb,
    const float* __restrict__ c_tab,
    const float* __restrict__ C_w, const float* __restrict__ D_skip,
    const float* __restrict__ ln_g, const float* __restrict__ ln_b,
    const short* __restrict__ Bf, const float* __restrict__ Wupd,
    const float* __restrict__ MT, unsigned int* __restrict__ h_out,
    short* __restrict__ Wcs, const int* __restrict__ edges,
    int* __restrict__ cnt, unsigned short* __restrict__ bucket,
    int* __restrict__ ovf_cnt, int* __restrict__ ovf){
  __shared__ unsigned int xsh[96][68];  // 26.1 KB x-tile (bf16 pairs)
  __shared__ float bsh[96][18];         // 6.75 KB; stride 18: 2-way (free)
  __shared__ float msh[32][18];         // 2.25 KB
  __shared__ float csh[KTR][DSTATE];    // 4 KB
  int bid = blockIdx.x, tid = threadIdx.x;

  if (bid >= SSM_PRECW){                // ---- bucket rider blocks
    int eid = (bid-SSM_PRECW)*256 + tid; // = B_SZ*NEDGE exactly
    int b2 = eid >> 13, i = eid & (NEDGE-1);
    const int* ei = edges + (size_t)b2*2*NEDGE;
    int s = ei[i]         & (SEQ-1);
    int d = ei[NEDGE + i] & (SEQ-1);
    int gdst = (b2 << 11) | d;
    int slot = atomicAdd(&cnt[gdst], 1);
    if (slot < BCAP) bucket[(size_t)gdst*BCAP + slot] = (unsigned short)s;
    else {
      int o = atomicAdd(ovf_cnt, 1);
      if (o < OVCAP) ovf[o] = ((b2 << 11) | s) | (gdst << 16);
    }
    return;
  }

  if (bid >= SSM_MAIN){                 // ---- precW rider blocks
    int idx = (bid-SSM_MAIN)*256 + tid; // 8192 fragment slots
    int c    = idx >> 10;
    int rem  = idx & 1023;
    int j    = rem >> 6;
    int lane = rem & 63;
    int n  = j*16 + (lane & 15);
    int kb = c*32 + (lane >> 4)*8;
    short v[8];
    #pragma unroll
    for (int jj = 0; jj < 8; ++jj){
      int k = kb + jj;
      float val = (k < 128) ? Wupd[(size_t)n*384 + k] : MT[(size_t)n*EMBED + (k-128)];
      v[jj] = f2b(val);
    }
    *(s16x8*)(Wcs + (size_t)idx*8) = *(s16x8*)v;
    return;
  }

  int b  = bid >> 6;                    // 64 blocks per batch
  int t0 = (bid & 63) * 32;
  int wv = tid >> 6, lane = tid & 63;
  int m = lane & 15, lg = lane >> 4;

  // ---- emb gather -> LDS x-tile: 96 rows (t0-64 .. t0+31), bit-identical
  {
    const int* tkb = tokens + b*SEQ;
    #pragma unroll
    for (int i = 0; i < 12; ++i){
      int gid = i*256 + tid;            // 3072 = 96 rows x 32 chunks
      int lr = gid >> 5, ch = gid & 31;
      int t = t0 - 64 + lr;
      uint2 o; o.x = 0u; o.y = 0u;
      if (t >= 0){
        int tok = tkb[t];
        tok = tok < 0 ? 0 : (tok >= VOCAB ? VOCAB-1 : tok);
        float4 v = *(const float4*)(emb + (size_t)tok*EMBED + ch*4);
        o.x = pack2(v.x, v.y); o.y = pack2(v.z, v.w);
      }
      *(uint2*)&xsh[lr][ch*2] = o;
    }
  }
  for (int i = tid; i < KTR*DSTATE; i += 256)
    csh[i >> 4][i & 15] = c_tab[i];

  // ---- C_w -> registers (32/lane): lane owns e0=lane*2, e0+1; contiguous
  int e0 = lane*2;
  float ct0[DSTATE], ct1[DSTATE];
  {
    const float4* c0 = (const float4*)(C_w + (size_t)e0*DSTATE);
    const float4* c1 = (const float4*)(C_w + (size_t)(e0+1)*DSTATE);
    #pragma unroll
    for (int i = 0; i < 4; ++i){
      float4 v0 = c0[i], v1 = c1[i];
      ct0[i*4+0]=v0.x; ct0[i*4+1]=v0.y; ct0[i*4+2]=v0.z; ct0[i*4+3]=v0.w;
      ct1[i*4+0]=v1.x; ct1[i*4+1]=v1.y; ct1[i*4+2]=v1.z; ct1[i*4+3]=v1.w;
    }
  }
  __syncthreads();

  // ---- bproj via MFMA: 6 tiles x 16 rows covering t0-64 .. t0+31 (from LDS)
  const s16x8* Bp = (const s16x8*)Bf;
  #pragma unroll
  for (int tt = 0; tt < 2; ++tt){
    int tile = wv*2 + tt;               // 0..7, use 0..5
    if (tile < 6){
      int trow = t0 - 64 + tile*16;
      f32x4 acc = (f32x4){0.f,0.f,0.f,0.f};
      if (trow >= 0){
        const short* xrow = (const short*)&xsh[tile*16 + m][0] + lg*8;
        #pragma unroll
        for (int c = 0; c < 4; ++c){
          s16x8 a = *(const s16x8*)(xrow + c*32);
          acc = __builtin_amdgcn_mfma_f32_16x16x32_bf16(a, Bp[c*64 + lane], acc, 0, 0, 0);
        }
      }
      // C/D: col = lane&15 (=d), row = lg*4 + r
      #pragma unroll
      for (int r = 0; r < 4; ++r)
        bsh[tile*16 + lg*4 + r][m] = scrub(acc[r]);
    }
  }
  __syncthreads();

  // ---- conv from LDS (taps in csh, uniform-address broadcast)
  {
    int d = tid & 15;
    #pragma unroll
    for (int it = 0; it < 2; ++it){
      int q = (tid + it*256) >> 4;      // 0..31
      int t = t0 + q;
      int base = 64 + q;
      int kmax = (t+1 < KTR) ? t+1 : KTR;
      float acc = 0.f;
      for (int k = 0; k < kmax; ++k) acc += csh[k][d] * bsh[base-k][d];
      msh[q][d] = scrub(acc);
    }
  }
  __syncthreads();

  // ---- ssm + LN: each wave 8 rows; x from LDS, C from registers
  float2 dsk = *(const float2*)&D_skip[e0];
  float2 lgv = *(const float2*)&ln_g[e0];
  float2 lbv = *(const float2*)&ln_b[e0];
  for (int q = wv*8; q < wv*8+8; ++q){
    int row = b*SEQ + t0 + q;
    unsigned int xp = xsh[64 + q][lane];
    float x0 = lo2f(xp), x1 = hi2f(xp);
    float y0 = dsk.x*x0, y1 = dsk.y*x1;
    #pragma unroll
    for (int d = 0; d < DSTATE; ++d){
      float md = msh[q][d];             // wave-uniform -> LDS broadcast
      y0 += md * ct0[d];
      y1 += md * ct1[d];
    }
    y0 = scrub(y0); y1 = scrub(y1);
    float s = y0+y1, s2 = y0*y0 + y1*y1;
    for (int off = 32; off; off >>= 1){ s += __shfl_down(s,off); s2 += __shfl_down(s2,off); }
    s = __shfl(s, 0); s2 = __shfl(s2, 0);
    float mu  = s * (1.f/EMBED);
    float var = s2 * (1.f/EMBED) - mu*mu;
    float inv = rsqrtf(fmaxf(var, 0.f) + LN_EPS);
    float o0 = scrub(lgv.x*(y0-mu)*inv + lbv.x);
    float o1 = scrub(lgv.y*(y1-mu)*inv + lbv.y);
    h_out[(size_t)row*(EMBED/2) + lane] = pack2(o0, o1);
  }
}

// ---------------------------------------------------------------------------
// Fused back half, r14: 32 rows/block for 2x Wcs reuse (grid 1024).
//   Each 16-row block previously swept all 128KB of Wcs from L2 for one
//   row-group; now each fragment feeds two row-groups. The r11 pipeline
//   extends: {issue pair0} -> h-MFMA grp0 -> {finish pair0, issue pair1}
//   -> h-MFMA grp1 -> {finish pair1} -> barrier -> g-MFMA both groups.
//   Same load values, same per-row t-order sums; pooling combines both
//   groups before one atomic (order within tolerance).
__global__ __launch_bounds__(256) void k_gupd(
    const short* __restrict__ h, const int* __restrict__ cnt,
    const unsigned short* __restrict__ bucket,
    const int* __restrict__ ovf_cnt, const int* __restrict__ ovf,
    const short* __restrict__ Wcs, const float* __restrict__ Wupd_b,
    const float* __restrict__ cls_w, const float* __restrict__ cls_b,
    float* __restrict__ out){
  __shared__ unsigned int gsh[32][68];   // padded g tile (b128-friendly)
  __shared__ float psum[HID];            // per-block pooled partials
  __shared__ float oacc[4][NCLS];        // per-wave class partials
  int tid = threadIdx.x;
  int wv = tid >> 6, lane = tid & 63;
  int row0 = blockIdx.x * 32;
  int b = row0 >> 11;                    // 32 | 2048: block is batch-pure
  int m = lane & 15, lg = lane >> 4;

  const unsigned int* hb  = (const unsigned int*)h + (size_t)b*SEQ*(EMBED/2);
  const unsigned int* h32 = (const unsigned int*)h;
  int hh = lane >> 5;                    // half-wave id 0/1
  int lw = lane & 31;                    // uint2 index within row
  int rbase = wv*8 + hh;                 // this half-wave's first rloc
  int on = *ovf_cnt; on = on > OVCAP ? OVCAP : on;   // ~always 0

  // ---- phase 1: issue first 4-deep gather batch for pair 0 (rloc rbase, rbase+2)
  int rA = row0 + rbase;
  int rB = row0 + rbase + 2;
  int nA = cnt[rA]; nA = nA > BCAP ? BCAP : nA;
  int nB = cnt[rB]; nB = nB > BCAP ? BCAP : nB;
  const unsigned short* bkA = bucket + (size_t)rA*BCAP;
  const unsigned short* bkB = bucket + (size_t)rB*BCAP;
  ushort4 sA = *(const ushort4*)bkA;     // BCAP=32 >= 4: always in-bounds
  ushort4 sB = *(const ushort4*)bkB;
  uint2 vA0 = *(const uint2*)&hb[(size_t)(0 < nA ? sA.x : 0)*(EMBED/2) + lw*2];
  uint2 vA1 = *(const uint2*)&hb[(size_t)(1 < nA ? sA.y : 0)*(EMBED/2) + lw*2];
  uint2 vA2 = *(const uint2*)&hb[(size_t)(2 < nA ? sA.z : 0)*(EMBED/2) + lw*2];
  uint2 vA3 = *(const uint2*)&hb[(size_t)(3 < nA ? sA.w : 0)*(EMBED/2) + lw*2];
  uint2 vB0 = *(const uint2*)&hb[(size_t)(0 < nB ? sB.x : 0)*(EMBED/2) + lw*2];
  uint2 vB1 = *(const uint2*)&hb[(size_t)(1 < nB ? sB.y : 0)*(EMBED/2) + lw*2];
  uint2 vB2 = *(const uint2*)&hb[(size_t)(2 < nB ? sB.z : 0)*(EMBED/2) + lw*2];
  uint2 vB3 = *(const uint2*)&hb[(size_t)(3 < nB ? sB.w : 0)*(EMBED/2) + lw*2];

  // ---- phase 2: h-part MFMAs, row-group 0 (rows row0..row0+15)
  const short* hrow0 = h + (size_t)(row0+m)*EMBED + lg*8;
  const short* hrow1 = h + (size_t)(row0+16+m)*EMBED + lg*8;
  int j0 = wv*4;
  f32x4 acc0[4], acc1[4];
  #pragma unroll
  for (int jj = 0; jj < 4; ++jj){
    acc0[jj] = (f32x4){0.f,0.f,0.f,0.f};
    acc1[jj] = (f32x4){0.f,0.f,0.f,0.f};
  }
  const s16x8* Bp = (const s16x8*)Wcs;
  #pragma unroll
  for (int c = 0; c < 4; ++c){
    s16x8 a = *(const s16x8*)(hrow0 + c*32);
    #pragma unroll
    for (int jj = 0; jj < 4; ++jj){
      s16x8 bfr = Bp[(c*16 + j0 + jj)*64 + lane];
      acc0[jj] = __builtin_amdgcn_mfma_f32_16x16x32_bf16(a, bfr, acc0[jj], 0, 0, 0);
    }
  }

  // ---- phase 3: finish pair 0; issue pair 1 (rloc rbase+4, rbase+6)
  {
    float ax0=0.f, ay0=0.f, ax1=0.f, ay1=0.f;
    if (0 < nA){ ax0 += lo2f(vA0.x); ay0 += hi2f(vA0.x); ax1 += lo2f(vA0.y); ay1 += hi2f(vA0.y); }
    if (1 < nA){ ax0 += lo2f(vA1.x); ay0 += hi2f(vA1.x); ax1 += lo2f(vA1.y); ay1 += hi2f(vA1.y); }
    if (2 < nA){ ax0 += lo2f(vA2.x); ay0 += hi2f(vA2.x); ax1 += lo2f(vA2.y); ay1 += hi2f(vA2.y); }
    if (3 < nA){ ax0 += lo2f(vA3.x); ay0 += hi2f(vA3.x); ax1 += lo2f(vA3.y); ay1 += hi2f(vA3.y); }
    for (int t = 4; t < nA; ++t){
      uint2 v = *(const uint2*)&hb[(size_t)bkA[t]*(EMBED/2) + lw*2];
      ax0 += lo2f(v.x); ay0 += hi2f(v.x); ax1 += lo2f(v.y); ay1 += hi2f(v.y);
    }
    for (int idx = 0; idx < on; ++idx){
      int pk = ovf[idx];
      if (((pk >> 16) & 0x7fff) == rA){
        uint2 v = *(const uint2*)&h32[(size_t)(pk & 0xffff)*(EMBED/2) + lw*2];
        ax0 += lo2f(v.x); ay0 += hi2f(v.x); ax1 += lo2f(v.y); ay1 += hi2f(v.y);
      }
    }
    uint2 o; o.x = pack2(scrub(ax0), scrub(ay0));
    o.y = pack2(scrub(ax1), scrub(ay1));
    *(uint2*)&gsh[rbase][lw*2] = o;
  }
  {
    float ax0=0.f, ay0=0.f, ax1=0.f, ay1=0.f;
    if (0 < nB){ ax0 += lo2f(vB0.x); ay0 += hi2f(vB0.x); ax1 += lo2f(vB0.y); ay1 += hi2f(vB0.y); }
    if (1 < nB){ ax0 += lo2f(vB1.x); ay0 += hi2f(vB1.x); ax1 += lo2f(vB1.y); ay1 += hi2f(vB1.y); }
    if (2 < nB){ ax0 += lo2f(vB2.x); ay0 += hi2f(vB2.x); ax1 += lo2f(vB2.y); ay1 += hi2f(vB2.y); }
    if (3 < nB){ ax0 += lo2f(vB3.x); ay0 += hi2f(vB3.x); ax1 += lo2f(vB3.y); ay1 += hi2f(vB3.y); }
    for (int t = 4; t < nB; ++t){
      uint2 v = *(const uint2*)&hb[(size_t)bkB[t]*(EMBED/2) + lw*2];
      ax0 += lo2f(v.x); ay0 += hi2f(v.x); ax1 += lo2f(v.y); ay1 += hi2f(v.y);
    }
    for (int idx = 0; idx < on; ++idx){
      int pk = ovf[idx];
      if (((pk >> 16) & 0x7fff) == rB){
        uint2 v = *(const uint2*)&h32[(size_t)(pk & 0xffff)*(EMBED/2) + lw*2];
        ax0 += lo2f(v.x); ay0 += hi2f(v.x); ax1 += lo2f(v.y); ay1 += hi2f(v.y);
      }
    }
    uint2 o; o.x = pack2(scrub(ax0), scrub(ay0));
    o.y = pack2(scrub(ax1), scrub(ay1));
    *(uint2*)&gsh[rbase + 2][lw*2] = o;
  }
  int rC = row0 + rbase + 4;
  int rD = row0 + rbase + 6;
  int nC = cnt[rC]; nC = nC > BCAP ? BCAP : nC;
  int nD = cnt[rD]; nD = nD > BCAP ? BCAP : nD;
  const unsigned short* bkC = bucket + (size_t)rC*BCAP;
  const unsigned short* bkD = bucket + (size_t)rD*BCAP;
  ushort4 sC = *(const ushort4*)bkC;
  ushort4 sD = *(const ushort4*)bkD;
  vA0 = *(const uint2*)&hb[(size_t)(0 < nC ? sC.x : 0)*(EMBED/2) + lw*2];
  vA1 = *(const uint2*)&hb[(size_t)(1 < nC ? sC.y : 0)*(EMBED/2) + lw*2];
  vA2 = *(const uint2*)&hb[(size_t)(2 < nC ? sC.z : 0)*(EMBED/2) + lw*2];
  vA3 = *(const uint2*)&hb[(size_t)(3 < nC ? sC.w : 0)*(EMBED/2) + lw*2];
  vB0 = *(const uint2*)&hb[(size_t)(0 < nD ? sD.x : 0)*(EMBED/2) + lw*2];
  vB1 = *(const uint2*)&hb[(size_t)(1 < nD ? sD.y : 0)*(EMBED/2) + lw*2];
  vB2 = *(const uint2*)&hb[(size_t)(2 < nD ? sD.z : 0)*(EMBED/2) + lw*2];
  vB3 = *(const uint2*)&hb[(size_t)(3 < nD ? sD.w : 0)*(EMBED/2) + lw*2];

  // ---- phase 4: h-part MFMAs, row-group 1 (rows row0+16..row0+31)
  #pragma unroll
  for (int c = 0; c < 4; ++c){
    s16x8 a = *(const s16x8*)(hrow1 + c*32);
    #pragma unroll
    for (int jj = 0; jj < 4; ++jj){
      s16x8 bfr = Bp[(c*16 + j0 + jj)*64 + lane];
      acc1[jj] = __builtin_amdgcn_mfma_f32_16x16x32_bf16(a, bfr, acc1[jj], 0, 0, 0);
    }
  }

  // ---- phase 5: finish pair 1
  {
    float ax0=0.f, ay0=0.f, ax1=0.f, ay1=0.f;
    if (0 < nC){ ax0 += lo2f(vA0.x); ay0 += hi2f(vA0.x); ax1 += lo2f(vA0.y); ay1 += hi2f(vA0.y); }
    if (1 < nC){ ax0 += lo2f(vA1.x); ay0 += hi2f(vA1.x); ax1 += lo2f(vA1.y); ay1 += hi2f(vA1.y); }
    if (2 < nC){ ax0 += lo2f(vA2.x); ay0 += hi2f(vA2.x); ax1 += lo2f(vA2.y); ay1 += hi2f(vA2.y); }
    if (3 < nC){ ax0 += lo2f(vA3.x); ay0 += hi2f(vA3.x); ax1 += lo2f(vA3.y); ay1 += hi2f(vA3.y); }
    for (int t = 4; t < nC; ++t){
      uint2 v = *(const uint2*)&hb[(size_t)bkC[t]*(EMBED/2) + lw*2];
      ax0 += lo2f(v.x); ay0 += hi2f(v.x); ax1 += lo2f(v.y); ay1 += hi2f(v.y);
    }
    for (int idx = 0; idx < on; ++idx){
      int pk = ovf[idx];
      if (((pk >> 16) & 0x7fff) == rC){
        uint2 v = *(const uint2*)&h32[(size_t)(pk & 0xffff)*(EMBED/2) + lw*2];
        ax0 += lo2f(v.x); ay0 += hi2f(v.x); ax1 += lo2f(v.y); ay1 += hi2f(v.y);
      }
    }
    uint2 o; o.x = pack2(scrub(ax0), scrub(ay0));
    o.y = pack2(scrub(ax1), scrub(ay1));
    *(uint2*)&gsh[rbase + 4][lw*2] = o;
  }
  {
    float ax0=0.f, ay0=0.f, ax1=0.f, ay1=0.f;
    if (0 < nD){ ax0 += lo2f(vB0.x); ay0 += hi2f(vB0.x); ax1 += lo2f(vB0.y); ay1 += hi2f(vB0.y); }
    if (1 < nD){ ax0 += lo2f(vB1.x); ay0 += hi2f(vB1.x); ax1 += lo2f(vB1.y); ay1 += hi2f(vB1.y); }
    if (2 < nD){ ax0 += lo2f(vB2.x); ay0 += hi2f(vB2.x); ax1 += lo2f(vB2.y); ay1 += hi2f(vB2.y); }
    if (3 < nD){ ax0 += lo2f(vB3.x); ay0 += hi2f(vB3.x); ax1 += lo2f(vB3.y); ay1 += hi2f(vB3.y); }
    for (int t = 4; t < nD; ++t){
      uint2 v = *(const uint2*)&hb[(size_t)bkD[t]*(EMBED/2) + lw*2];
      ax0 += lo2f(v.x); ay0 += hi2f(v.x); ax1 += lo2f(v.y); ay1 += hi2f(v.y);
    }
    for (int idx = 0; idx < on; ++idx){
      int pk = ovf[idx];
      if (((pk >> 16) & 0x7fff) == rD){
        uint2 v = *(const uint2*)&h32[(size_t)(pk & 0xffff)*(EMBED/2) + lw*2];
        ax0 += lo2f(v.x); ay0 += hi2f(v.x); ax1 += lo2f(v.y); ay1 += hi2f(v.y);
      }
    }
    uint2 o; o.x = pack2(scrub(ax0), scrub(ay0));
    o.y = pack2(scrub(ax1), scrub(ay1));
    *(uint2*)&gsh[rbase + 6][lw*2] = o;
  }
  __syncthreads();

  // ---- phase 6: g-part MFMAs (c=4..7), both row-groups share each fragment
  #pragma unroll
  for (int c = 4; c < 8; ++c){
    s16x8 a0 = *(const s16x8*)&gsh[m][(c-4)*16 + lg*4];
    s16x8 a1 = *(const s16x8*)&gsh[16 + m][(c-4)*16 + lg*4];
    #pragma unroll
    for (int jj = 0; jj < 4; ++jj){
      s16x8 bfr = Bp[(c*16 + j0 + jj)*64 + lane];
      acc0[jj] = __builtin_amdgcn_mfma_f32_16x16x32_bf16(a0, bfr, acc0[jj], 0, 0, 0);
      acc1[jj] = __builtin_amdgcn_mfma_f32_16x16x32_bf16(a1, bfr, acc1[jj], 0, 0, 0);
    }
  }

  // ---- relu + row-sum over this block's 32 rows -> psum[n] (disjoint n/wave)
  #pragma unroll
  for (int jj = 0; jj < 4; ++jj){
    int n = (j0 + jj)*16 + m;
    float bias = Wupd_b[n];
    float v = 0.f;
    #pragma unroll
    for (int r = 0; r < 4; ++r) v += fmaxf(acc0[jj][r] + bias, 0.f);
    #pragma unroll
    for (int r = 0; r < 4; ++r) v += fmaxf(acc1[jj][r] + bias, 0.f);
    v += __shfl_down(v, 32);
    v += __shfl_down(v, 16);
    if (lane < 16) psum[n] = scrub(v);
  }
  __syncthreads();

  // ---- linear classifier epilogue: out[b][c] += (psum . cls_w[c]) / SEQ
  {
    float pn = psum[tid];                // tid = n, all 256 covered
    #pragma unroll
    for (int c = 0; c < NCLS; ++c){
      float t = pn * cls_w[c*HID + tid];
      for (int off = 32; off; off >>= 1) t += __shfl_down(t, off);
      if (lane == 0) oacc[wv][c] = t;
    }
    __syncthreads();
    if (tid < NCLS){
      float s = oacc[0][tid] + oacc[1][tid] + oacc[2][tid] + oacc[3][tid];
      atomicAdd(&out[b*NCLS + tid], scrub(s * (1.0f/SEQ)));
    }
    if ((blockIdx.x & 63) == 0 && tid < NCLS)      // once per batch: bias
      atomicAdd(&out[b*NCLS + tid], cls_b[tid]);
  }
}

// ---------------------------------------------------------------------------
extern "C" void kernel_launch(void* const* d_in, const int* in_sizes, int n_in,
                              void* d_out, int out_size, void* d_ws, size_t ws_size,
                              hipStream_t stream) {
  const int*   tokens = (const int*)d_in[0];
  const int*   edges  = (const int*)d_in[2];
  const float* emb    = (const float*)d_in[3];
  const float* A_log  = (const float*)d_in[4];
  const float* B_w    = (const float*)d_in[5];
  const float* C_w    = (const float*)d_in[6];
  const float* D_skip = (const float*)d_in[7];
  const float* ln_g   = (const float*)d_in[8];
  const float* ln_b   = (const float*)d_in[9];
  const float* Wmsg   = (const float*)d_in[10];
  const float* Wupd   = (const float*)d_in[11];
  const float* Wupd_b = (const float*)d_in[12];
  const float* cls_w  = (const float*)d_in[13];
  const float* cls_b  = (const float*)d_in[14];
  float* out = (float*)d_out;

  // workspace layout (~10.4 MB)
  char* ws = (char*)d_ws;
  float* c_tab = (float*)ws;  ws += 16*1024;                 // 4 KB used
  float* MT    = (float*)ws;  ws += (size_t)HID*EMBED*4;     // 128 KB
  short* Wcs   = (short*)ws;  ws += (size_t)HID*HID*2;       // 128 KB
  short* Bf    = (short*)ws;  ws += 16*1024;                 // 4 KB used
  int*   cnt   = (int*)ws;    ws += (size_t)NROW*4;          // 128 KB
  int*   ovf_cnt = (int*)ws;  ws += 64;
  int*   ovf   = (int*)ws;    ws += OVCAP*4;                 // 4 KB
  unsigned short* bucket = (unsigned short*)ws; ws += (size_t)NROW*BCAP*2; // 2 MB
  short* h_bf  = (short*)ws;  ws += (size_t)NROW*EMBED*2;    // 8 MB

  // zeroing of cnt/ovf_cnt/ovf/out is done by k_prep rider blocks (r10)
  hipLaunchKernelGGL(k_prep, dim3(PB_TOTAL), dim3(256), 0, stream,
                     A_log, B_w, Wmsg, Wupd, c_tab, Bf, MT, cnt, out);
  hipLaunchKernelGGL(k_ssm_fused, dim3(SSM_TOTAL), dim3(256), 0, stream,
                     tokens, emb, c_tab, C_w, D_skip, ln_g, ln_b, Bf, Wupd, MT,
                     (unsigned int*)h_bf, Wcs, edges, cnt, bucket, ovf_cnt, ovf);
  hipLaunchKernelGGL(k_gupd, dim3(NROW/32), dim3(256), 0, stream,
                     h_bf, cnt, bucket, ovf_cnt, ovf, Wcs, Wupd_b,
                     cls_w, cls_b, out);
}

// Round 15
// 168.021 us; speedup vs baseline: 1.0590x; 1.0590x over previous
//
#include <hip/hip_runtime.h>

#define B_SZ   16
#define SEQ    2048
#define VOCAB  50257
#define EMBED  128
#define DSTATE 16
#define HID    256
#define NCLS   10
#define NEDGE  8192
#define KTR    64          // scan truncation: A<=0.55 -> A^64 < 2e-17
#define LN_EPS 1e-5f
#define NROW   (B_SZ*SEQ)  // 32768
#define BCAP   32          // bucket capacity per dst (Poisson lambda=4)
#define OVCAP  1024        // overflow fallback capacity

// k_prep phase block ranges
#define PB_PRECM  128                   // 256 hp, 2 per block
#define PB_CTAB   (PB_PRECM + 16)       // 16 d
#define PB_PRECB  (PB_CTAB + 1)         // +1 precB          = 145
#define PB_ZNINT  33808                 // cnt(32768)+ovf_cnt(16)+ovf(1024)
#define PB_ZBLK   34                    // ceil(33808/1024)
#define PB_ZOUT   (PB_PRECB + PB_ZBLK)  // 179: zero out[160]
#define PB_TOTAL  (PB_ZOUT + 1)         // 180

// k_ssm_fused block ranges
#define SSM_MAIN  1024                  // 16 batches x 64 tiles of 32 rows
#define SSM_PRECW (SSM_MAIN + 32)       // 1056
#define SSM_TOTAL (SSM_PRECW + 512)     // 1568 (bucket riders)

typedef float  f32x4 __attribute__((ext_vector_type(4)));
typedef short  s16x8 __attribute__((ext_vector_type(8)));

__device__ __forceinline__ float scrub(float x){
  return (x == x && fabsf(x) < 1e30f) ? x : 0.f;
}
// fp32 -> bf16 bits, round-to-nearest-even
__device__ __forceinline__ short f2b(float f){
  unsigned int u = __float_as_uint(f);
  unsigned int r = (u + 0x7fffu + ((u >> 16) & 1u)) >> 16;
  return (short)r;
}
__device__ __forceinline__ unsigned int pack2(float a, float b){
  return (unsigned int)(unsigned short)f2b(a)
       | ((unsigned int)(unsigned short)f2b(b) << 16);
}
__device__ __forceinline__ float lo2f(unsigned int v){ return __uint_as_float(v << 16); }
__device__ __forceinline__ float hi2f(unsigned int v){ return __uint_as_float(v & 0xffff0000u); }

// ---------------------------------------------------------------------------
// Prep kernel: precM + ctab + precB + workspace/out zeroing riders (r10).
// precM stays here (r12 lesson: its 32768-thread parallelism is load-bearing).
__global__ __launch_bounds__(256) void k_prep(
    const float* __restrict__ A_log, const float* __restrict__ B_w,
    const float* __restrict__ Wmsg, const float* __restrict__ Wupd,
    float* __restrict__ c_tab, short* __restrict__ Bf, float* __restrict__ MT,
    int* __restrict__ cnt, float* __restrict__ out){
  int bid = blockIdx.x, tid = threadIdx.x;
  if (bid < PB_PRECM){                           // ---- precM: 2 hp per block
    int hp = bid*2 + (tid >> 7);                 // 0..255
    int e  = tid & 127;
    const float* w2 = Wupd + (size_t)hp*384 + 128;
    float acc = 0.f;
    for (int h1 = 0; h1 < HID; ++h1)
      acc += Wmsg[h1*EMBED + e] * w2[h1];
    MT[(size_t)hp*EMBED + e] = scrub(acc);
  } else if (bid < PB_CTAB){                     // ---- ctab (wave 0 only)
    if (tid < 64){
      int d = bid - PB_PRECM, lane = tid;        // d = 0..15
      float a0 = scrub(expf(-expf(A_log[(2*lane+0)*DSTATE + d])));
      float a1 = scrub(expf(-expf(A_log[(2*lane+1)*DSTATE + d])));
      float p0 = 1.f, p1 = 1.f;
      for (int k = 0; k < KTR; ++k){
        float s = p0 + p1;
        for (int off = 32; off; off >>= 1) s += __shfl_down(s, off);
        if (lane == 0) c_tab[k*DSTATE + d] = scrub(s * (1.0f/128.0f));
        p0 *= a0; p1 *= a1;
      }
    }
  } else if (bid < PB_PRECB){                    // ---- precB (256 slots)
    int idx = tid;
    int c = idx >> 6, lane = idx & 63;
    int n = lane & 15;
    int kb = c*32 + (lane >> 4)*8;
    short v[8];
    #pragma unroll
    for (int jj = 0; jj < 8; ++jj) v[jj] = f2b(B_w[(size_t)n*EMBED + kb + jj]);
    *(s16x8*)(Bf + (size_t)idx*8) = *(s16x8*)v;
  } else if (bid < PB_ZOUT){                     // ---- zero cnt/ovf_cnt/ovf
    int idx4 = (bid-PB_PRECB)*1024 + tid*4;      // 16B-aligned int offset
    if (idx4 < PB_ZNINT){
      uint4 z; z.x = z.y = z.z = z.w = 0u;
      *(uint4*)&cnt[idx4] = z;
    }
  } else {                                       // ---- zero out[160]
    if (tid < B_SZ*NCLS) out[tid] = 0.f;
  }
}

// ---------------------------------------------------------------------------
// Fused emb-cast + bproj(MFMA) + conv + ssm + LayerNorm. (r10 exact)
__global__ __launch_bounds__(256) void k_ssm_fused(
    const int* __restrict__ tokens, const float* __restrict__ emb,
    const float* __restrict__ c_tab,
    const float* __restrict__ C_w, const float* __restrict__ D_skip,
    const float* __restrict__ ln_g, const float* __restrict__ ln_b,
    const short* __restrict__ Bf, const float* __restrict__ Wupd,
    const float* __restrict__ MT, unsigned int* __restrict__ h_out,
    short* __restrict__ Wcs, const int* __restrict__ edges,
    int* __restrict__ cnt, unsigned short* __restrict__ bucket,
    int* __restrict__ ovf_cnt, int* __restrict__ ovf){
  __shared__ unsigned int xsh[96][68];  // 26.1 KB x-tile (bf16 pairs)
  __shared__ float bsh[96][18];         // 6.75 KB; stride 18: 2-way (free)
  __shared__ float msh[32][18];         // 2.25 KB
  __shared__ float csh[KTR][DSTATE];    // 4 KB
  int bid = blockIdx.x, tid = threadIdx.x;

  if (bid >= SSM_PRECW){                // ---- bucket rider blocks
    int eid = (bid-SSM_PRECW)*256 + tid; // = B_SZ*NEDGE exactly
    int b2 = eid >> 13, i = eid & (NEDGE-1);
    const int* ei = edges + (size_t)b2*2*NEDGE;
    int s = ei[i]         & (SEQ-1);
    int d = ei[NEDGE + i] & (SEQ-1);
    int gdst = (b2 << 11) | d;
    int slot = atomicAdd(&cnt[gdst], 1);
    if (slot < BCAP) bucket[(size_t)gdst*BCAP + slot] = (unsigned short)s;
    else {
      int o = atomicAdd(ovf_cnt, 1);
      if (o < OVCAP) ovf[o] = ((b2 << 11) | s) | (gdst << 16);
    }
    return;
  }

  if (bid >= SSM_MAIN){                 // ---- precW rider blocks
    int idx = (bid-SSM_MAIN)*256 + tid; // 8192 fragment slots
    int c    = idx >> 10;
    int rem  = idx & 1023;
    int j    = rem >> 6;
    int lane = rem & 63;
    int n  = j*16 + (lane & 15);
    int kb = c*32 + (lane >> 4)*8;
    short v[8];
    #pragma unroll
    for (int jj = 0; jj < 8; ++jj){
      int k = kb + jj;
      float val = (k < 128) ? Wupd[(size_t)n*384 + k] : MT[(size_t)n*EMBED + (k-128)];
      v[jj] = f2b(val);
    }
    *(s16x8*)(Wcs + (size_t)idx*8) = *(s16x8*)v;
    return;
  }

  int b  = bid >> 6;                    // 64 blocks per batch
  int t0 = (bid & 63) * 32;
  int wv = tid >> 6, lane = tid & 63;
  int m = lane & 15, lg = lane >> 4;

  // ---- emb gather -> LDS x-tile: 96 rows (t0-64 .. t0+31), bit-identical
  {
    const int* tkb = tokens + b*SEQ;
    #pragma unroll
    for (int i = 0; i < 12; ++i){
      int gid = i*256 + tid;            // 3072 = 96 rows x 32 chunks
      int lr = gid >> 5, ch = gid & 31;
      int t = t0 - 64 + lr;
      uint2 o; o.x = 0u; o.y = 0u;
      if (t >= 0){
        int tok = tkb[t];
        tok = tok < 0 ? 0 : (tok >= VOCAB ? VOCAB-1 : tok);
        float4 v = *(const float4*)(emb + (size_t)tok*EMBED + ch*4);
        o.x = pack2(v.x, v.y); o.y = pack2(v.z, v.w);
      }
      *(uint2*)&xsh[lr][ch*2] = o;
    }
  }
  for (int i = tid; i < KTR*DSTATE; i += 256)
    csh[i >> 4][i & 15] = c_tab[i];

  // ---- C_w -> registers (32/lane): lane owns e0=lane*2, e0+1; contiguous
  int e0 = lane*2;
  float ct0[DSTATE], ct1[DSTATE];
  {
    const float4* c0 = (const float4*)(C_w + (size_t)e0*DSTATE);
    const float4* c1 = (const float4*)(C_w + (size_t)(e0+1)*DSTATE);
    #pragma unroll
    for (int i = 0; i < 4; ++i){
      float4 v0 = c0[i], v1 = c1[i];
      ct0[i*4+0]=v0.x; ct0[i*4+1]=v0.y; ct0[i*4+2]=v0.z; ct0[i*4+3]=v0.w;
      ct1[i*4+0]=v1.x; ct1[i*4+1]=v1.y; ct1[i*4+2]=v1.z; ct1[i*4+3]=v1.w;
    }
  }
  __syncthreads();

  // ---- bproj via MFMA: 6 tiles x 16 rows covering t0-64 .. t0+31 (from LDS)
  const s16x8* Bp = (const s16x8*)Bf;
  #pragma unroll
  for (int tt = 0; tt < 2; ++tt){
    int tile = wv*2 + tt;               // 0..7, use 0..5
    if (tile < 6){
      int trow = t0 - 64 + tile*16;
      f32x4 acc = (f32x4){0.f,0.f,0.f,0.f};
      if (trow >= 0){
        const short* xrow = (const short*)&xsh[tile*16 + m][0] + lg*8;
        #pragma unroll
        for (int c = 0; c < 4; ++c){
          s16x8 a = *(const s16x8*)(xrow + c*32);
          acc = __builtin_amdgcn_mfma_f32_16x16x32_bf16(a, Bp[c*64 + lane], acc, 0, 0, 0);
        }
      }
      // C/D: col = lane&15 (=d), row = lg*4 + r
      #pragma unroll
      for (int r = 0; r < 4; ++r)
        bsh[tile*16 + lg*4 + r][m] = scrub(acc[r]);
    }
  }
  __syncthreads();

  // ---- conv from LDS (taps in csh, uniform-address broadcast)
  {
    int d = tid & 15;
    #pragma unroll
    for (int it = 0; it < 2; ++it){
      int q = (tid + it*256) >> 4;      // 0..31
      int t = t0 + q;
      int base = 64 + q;
      int kmax = (t+1 < KTR) ? t+1 : KTR;
      float acc = 0.f;
      for (int k = 0; k < kmax; ++k) acc += csh[k][d] * bsh[base-k][d];
      msh[q][d] = scrub(acc);
    }
  }
  __syncthreads();

  // ---- ssm + LN: each wave 8 rows; x from LDS, C from registers
  float2 dsk = *(const float2*)&D_skip[e0];
  float2 lgv = *(const float2*)&ln_g[e0];
  float2 lbv = *(const float2*)&ln_b[e0];
  for (int q = wv*8; q < wv*8+8; ++q){
    int row = b*SEQ + t0 + q;
    unsigned int xp = xsh[64 + q][lane];
    float x0 = lo2f(xp), x1 = hi2f(xp);
    float y0 = dsk.x*x0, y1 = dsk.y*x1;
    #pragma unroll
    for (int d = 0; d < DSTATE; ++d){
      float md = msh[q][d];             // wave-uniform -> LDS broadcast
      y0 += md * ct0[d];
      y1 += md * ct1[d];
    }
    y0 = scrub(y0); y1 = scrub(y1);
    float s = y0+y1, s2 = y0*y0 + y1*y1;
    for (int off = 32; off; off >>= 1){ s += __shfl_down(s,off); s2 += __shfl_down(s2,off); }
    s = __shfl(s, 0); s2 = __shfl(s2, 0);
    float mu  = s * (1.f/EMBED);
    float var = s2 * (1.f/EMBED) - mu*mu;
    float inv = rsqrtf(fmaxf(var, 0.f) + LN_EPS);
    float o0 = scrub(lgv.x*(y0-mu)*inv + lbv.x);
    float o1 = scrub(lgv.y*(y1-mu)*inv + lbv.y);
    h_out[(size_t)row*(EMBED/2) + lane] = pack2(o0, o1);
  }
}

// ---------------------------------------------------------------------------
// Fused back half, r15: r11 pipeline + XCD-aware block swizzle.
//   r14 counters: FETCH 20.7MB vs ~10.5MB minimal -> h re-fetched from HBM
//   ~2x because round-robin block->XCD spreads concurrent blocks over ~5-6
//   batches (> 4MB L2/XCD). Swizzle swz=(bid&7)*256+(bid>>3) gives each XCD
//   a contiguous 256-block chunk = 2 batch h-panels (1MB) + Wcs (128KB) ->
//   L2-resident gathers. Pure reindexing: all sums bit-identical.
__global__ __launch_bounds__(256) void k_gupd(
    const short* __restrict__ h, const int* __restrict__ cnt,
    const unsigned short* __restrict__ bucket,
    const int* __restrict__ ovf_cnt, const int* __restrict__ ovf,
    const short* __restrict__ Wcs, const float* __restrict__ Wupd_b,
    const float* __restrict__ cls_w, const float* __restrict__ cls_b,
    float* __restrict__ out){
  __shared__ unsigned int gsh[16][68];   // padded g tile (b128-friendly)
  __shared__ float psum[HID];            // per-block pooled partials
  __shared__ float oacc[4][NCLS];        // per-wave class partials
  int tid = threadIdx.x;
  int wv = tid >> 6, lane = tid & 63;
  int bid0 = blockIdx.x;
  int swz  = ((bid0 & 7) << 8) | (bid0 >> 3);   // bijective: 2048 % 8 == 0
  int row0 = swz * 16;
  int b = row0 >> 11;                    // 16 | 2048: block is batch-pure
  int m = lane & 15, lg = lane >> 4;

  const unsigned int* hb  = (const unsigned int*)h + (size_t)b*SEQ*(EMBED/2);
  const unsigned int* h32 = (const unsigned int*)h;
  int hh = lane >> 5;                    // half-wave id 0/1
  int lw = lane & 31;                    // uint2 index within row

  // ---- phase 1: issue first 4-deep gather batch for both rows
  int rA = row0 + wv*4 + hh;
  int rB = row0 + wv*4 + 2 + hh;
  int nA = cnt[rA]; nA = nA > BCAP ? BCAP : nA;
  int nB = cnt[rB]; nB = nB > BCAP ? BCAP : nB;
  const unsigned short* bkA = bucket + (size_t)rA*BCAP;
  const unsigned short* bkB = bucket + (size_t)rB*BCAP;
  ushort4 sA = *(const ushort4*)bkA;     // BCAP=32 >= 4: always in-bounds
  ushort4 sB = *(const ushort4*)bkB;
  uint2 vA0 = *(const uint2*)&hb[(size_t)(0 < nA ? sA.x : 0)*(EMBED/2) + lw*2];
  uint2 vA1 = *(const uint2*)&hb[(size_t)(1 < nA ? sA.y : 0)*(EMBED/2) + lw*2];
  uint2 vA2 = *(const uint2*)&hb[(size_t)(2 < nA ? sA.z : 0)*(EMBED/2) + lw*2];
  uint2 vA3 = *(const uint2*)&hb[(size_t)(3 < nA ? sA.w : 0)*(EMBED/2) + lw*2];
  uint2 vB0 = *(const uint2*)&hb[(size_t)(0 < nB ? sB.x : 0)*(EMBED/2) + lw*2];
  uint2 vB1 = *(const uint2*)&hb[(size_t)(1 < nB ? sB.y : 0)*(EMBED/2) + lw*2];
  uint2 vB2 = *(const uint2*)&hb[(size_t)(2 < nB ? sB.z : 0)*(EMBED/2) + lw*2];
  uint2 vB3 = *(const uint2*)&hb[(size_t)(3 < nB ? sB.w : 0)*(EMBED/2) + lw*2];

  // ---- phase 2: h-part MFMAs (c=0..3) — independent of the gather
  const short* hrow = h + (size_t)(row0+m)*EMBED + lg*8;
  int j0 = wv*4;
  f32x4 acc[4];
  #pragma unroll
  for (int jj = 0; jj < 4; ++jj) acc[jj] = (f32x4){0.f,0.f,0.f,0.f};
  const s16x8* Bp = (const s16x8*)Wcs;
  #pragma unroll
  for (int c = 0; c < 4; ++c){
    s16x8 a = *(const s16x8*)(hrow + c*32);
    #pragma unroll
    for (int jj = 0; jj < 4; ++jj){
      s16x8 bfr = Bp[(c*16 + j0 + jj)*64 + lane];
      acc[jj] = __builtin_amdgcn_mfma_f32_16x16x32_bf16(a, bfr, acc[jj], 0, 0, 0);
    }
  }

  // ---- phase 3: finish gather (original t-order), pack to LDS, barrier
  int on = *ovf_cnt; on = on > OVCAP ? OVCAP : on;   // ~always 0
  {
    float ax0=0.f, ay0=0.f, ax1=0.f, ay1=0.f;
    if (0 < nA){ ax0 += lo2f(vA0.x); ay0 += hi2f(vA0.x); ax1 += lo2f(vA0.y); ay1 += hi2f(vA0.y); }
    if (1 < nA){ ax0 += lo2f(vA1.x); ay0 += hi2f(vA1.x); ax1 += lo2f(vA1.y); ay1 += hi2f(vA1.y); }
    if (2 < nA){ ax0 += lo2f(vA2.x); ay0 += hi2f(vA2.x); ax1 += lo2f(vA2.y); ay1 += hi2f(vA2.y); }
    if (3 < nA){ ax0 += lo2f(vA3.x); ay0 += hi2f(vA3.x); ax1 += lo2f(vA3.y); ay1 += hi2f(vA3.y); }
    for (int t = 4; t < nA; ++t){
      uint2 v = *(const uint2*)&hb[(size_t)bkA[t]*(EMBED/2) + lw*2];
      ax0 += lo2f(v.x); ay0 += hi2f(v.x); ax1 += lo2f(v.y); ay1 += hi2f(v.y);
    }
    for (int idx = 0; idx < on; ++idx){
      int pk = ovf[idx];
      if (((pk >> 16) & 0x7fff) == rA){
        uint2 v = *(const uint2*)&h32[(size_t)(pk & 0xffff)*(EMBED/2) + lw*2];
        ax0 += lo2f(v.x); ay0 += hi2f(v.x); ax1 += lo2f(v.y); ay1 += hi2f(v.y);
      }
    }
    uint2 o; o.x = pack2(scrub(ax0), scrub(ay0));
    o.y = pack2(scrub(ax1), scrub(ay1));
    *(uint2*)&gsh[rA - row0][lw*2] = o;
  }
  {
    float ax0=0.f, ay0=0.f, ax1=0.f, ay1=0.f;
    if (0 < nB){ ax0 += lo2f(vB0.x); ay0 += hi2f(vB0.x); ax1 += lo2f(vB0.y); ay1 += hi2f(vB0.y); }
    if (1 < nB){ ax0 += lo2f(vB1.x); ay0 += hi2f(vB1.x); ax1 += lo2f(vB1.y); ay1 += hi2f(vB1.y); }
    if (2 < nB){ ax0 += lo2f(vB2.x); ay0 += hi2f(vB2.x); ax1 += lo2f(vB2.y); ay1 += hi2f(vB2.y); }
    if (3 < nB){ ax0 += lo2f(vB3.x); ay0 += hi2f(vB3.x); ax1 += lo2f(vB3.y); ay1 += hi2f(vB3.y); }
    for (int t = 4; t < nB; ++t){
      uint2 v = *(const uint2*)&hb[(size_t)bkB[t]*(EMBED/2) + lw*2];
      ax0 += lo2f(v.x); ay0 += hi2f(v.x); ax1 += lo2f(v.y); ay1 += hi2f(v.y);
    }
    for (int idx = 0; idx < on; ++idx){
      int pk = ovf[idx];
      if (((pk >> 16) & 0x7fff) == rB){
        uint2 v = *(const uint2*)&h32[(size_t)(pk & 0xffff)*(EMBED/2) + lw*2];
        ax0 += lo2f(v.x); ay0 += hi2f(v.x); ax1 += lo2f(v.y); ay1 += hi2f(v.y);
      }
    }
    uint2 o; o.x = pack2(scrub(ax0), scrub(ay0));
    o.y = pack2(scrub(ax1), scrub(ay1));
    *(uint2*)&gsh[rB - row0][lw*2] = o;
  }
  __syncthreads();

  // ---- phase 4: g-part MFMAs (c=4..7) from LDS (same c-order as before)
  #pragma unroll
  for (int c = 4; c < 8; ++c){
    s16x8 a = *(const s16x8*)&gsh[m][(c-4)*16 + lg*4];
    #pragma unroll
    for (int jj = 0; jj < 4; ++jj){
      s16x8 bfr = Bp[(c*16 + j0 + jj)*64 + lane];
      acc[jj] = __builtin_amdgcn_mfma_f32_16x16x32_bf16(a, bfr, acc[jj], 0, 0, 0);
    }
  }

  // ---- relu + row-sum over this block's 16 rows -> psum[n] (disjoint n/wave)
  #pragma unroll
  for (int jj = 0; jj < 4; ++jj){
    int n = (j0 + jj)*16 + m;
    float bias = Wupd_b[n];
    float v = 0.f;
    #pragma unroll
    for (int r = 0; r < 4; ++r) v += fmaxf(acc[jj][r] + bias, 0.f);
    v += __shfl_down(v, 32);
    v += __shfl_down(v, 16);
    if (lane < 16) psum[n] = scrub(v);
  }
  __syncthreads();

  // ---- linear classifier epilogue: out[b][c] += (psum . cls_w[c]) / SEQ
  {
    float pn = psum[tid];                // tid = n, all 256 covered
    #pragma unroll
    for (int c = 0; c < NCLS; ++c){
      float t = pn * cls_w[c*HID + tid];
      for (int off = 32; off; off >>= 1) t += __shfl_down(t, off);
      if (lane == 0) oacc[wv][c] = t;
    }
    __syncthreads();
    if (tid < NCLS){
      float s = oacc[0][tid] + oacc[1][tid] + oacc[2][tid] + oacc[3][tid];
      atomicAdd(&out[b*NCLS + tid], scrub(s * (1.0f/SEQ)));
    }
    if ((swz & 127) == 0 && tid < NCLS)            // once per batch: bias
      atomicAdd(&out[b*NCLS + tid], cls_b[tid]);
  }
}

// ---------------------------------------------------------------------------
extern "C" void kernel_launch(void* const* d_in, const int* in_sizes, int n_in,
                              void* d_out, int out_size, void* d_ws, size_t ws_size,
                              hipStream_t stream) {
  const int*   tokens = (const int*)d_in[0];
  const int*   edges  = (const int*)d_in[2];
  const float* emb    = (const float*)d_in[3];
  const float* A_log  = (const float*)d_in[4];
  const float* B_w    = (const float*)d_in[5];
  const float* C_w    = (const float*)d_in[6];
  const float* D_skip = (const float*)d_in[7];
  const float* ln_g   = (const float*)d_in[8];
  const float* ln_b   = (const float*)d_in[9];
  const float* Wmsg   = (const float*)d_in[10];
  const float* Wupd   = (const float*)d_in[11];
  const float* Wupd_b = (const float*)d_in[12];
  const float* cls_w  = (const float*)d_in[13];
  const float* cls_b  = (const float*)d_in[14];
  float* out = (float*)d_out;

  // workspace layout (~10.4 MB)
  char* ws = (char*)d_ws;
  float* c_tab = (float*)ws;  ws += 16*1024;                 // 4 KB used
  float* MT    = (float*)ws;  ws += (size_t)HID*EMBED*4;     // 128 KB
  short* Wcs   = (short*)ws;  ws += (size_t)HID*HID*2;       // 128 KB
  short* Bf    = (short*)ws;  ws += 16*1024;                 // 4 KB used
  int*   cnt   = (int*)ws;    ws += (size_t)NROW*4;          // 128 KB
  int*   ovf_cnt = (int*)ws;  ws += 64;
  int*   ovf   = (int*)ws;    ws += OVCAP*4;                 // 4 KB
  unsigned short* bucket = (unsigned short*)ws; ws += (size_t)NROW*BCAP*2; // 2 MB
  short* h_bf  = (short*)ws;  ws += (size_t)NROW*EMBED*2;    // 8 MB

  // zeroing of cnt/ovf_cnt/ovf/out is done by k_prep rider blocks (r10)
  hipLaunchKernelGGL(k_prep, dim3(PB_TOTAL), dim3(256), 0, stream,
                     A_log, B_w, Wmsg, Wupd, c_tab, Bf, MT, cnt, out);
  hipLaunchKernelGGL(k_ssm_fused, dim3(SSM_TOTAL), dim3(256), 0, stream,
                     tokens, emb, c_tab, C_w, D_skip, ln_g, ln_b, Bf, Wupd, MT,
                     (unsigned int*)h_bf, Wcs, edges, cnt, bucket, ovf_cnt, ovf);
  hipLaunchKernelGGL(k_gupd, dim3(NROW/16), dim3(256), 0, stream,
                     h_bf, cnt, bucket, ovf_cnt, ovf, Wcs, Wupd_b,
                     cls_w, cls_b, out);
}

// Round 16
// 164.392 us; speedup vs baseline: 1.0824x; 1.0221x over previous
//
#include <hip/hip_runtime.h>

#define B_SZ   16
#define SEQ    2048
#define VOCAB  50257
#define EMBED  128
#define DSTATE 16
#define HID    256
#define NCLS   10
#define NEDGE  8192
#define KTR    64          // scan truncation: A<=0.55 -> A^64 < 2e-17
#define LN_EPS 1e-5f
#define NROW   (B_SZ*SEQ)  // 32768
#define BCAP   32          // bucket capacity per dst (Poisson lambda=4)
#define OVCAP  1024        // overflow fallback capacity

// k_prep phase block ranges
#define PB_PRECM  128                   // 256 hp, 2 per block
#define PB_CTAB   (PB_PRECM + 16)       // 16 d
#define PB_PRECB  (PB_CTAB + 1)         // +1 precB          = 145
#define PB_ZNINT  33808                 // cnt(32768)+ovf_cnt(16)+ovf(1024)
#define PB_ZBLK   34                    // ceil(33808/1024)
#define PB_ZOUT   (PB_PRECB + PB_ZBLK)  // 179: zero out[160]
#define PB_TOTAL  (PB_ZOUT + 1)         // 180

// k_ssm_fused block ranges
#define SSM_MAIN  1024                  // 16 batches x 64 tiles of 32 rows
#define SSM_PRECW (SSM_MAIN + 32)       // 1056
#define SSM_TOTAL (SSM_PRECW + 512)     // 1568 (bucket riders)

typedef float  f32x4 __attribute__((ext_vector_type(4)));
typedef short  s16x8 __attribute__((ext_vector_type(8)));

__device__ __forceinline__ float scrub(float x){
  return (x == x && fabsf(x) < 1e30f) ? x : 0.f;
}
// fp32 -> bf16 bits, round-to-nearest-even
__device__ __forceinline__ short f2b(float f){
  unsigned int u = __float_as_uint(f);
  unsigned int r = (u + 0x7fffu + ((u >> 16) & 1u)) >> 16;
  return (short)r;
}
__device__ __forceinline__ unsigned int pack2(float a, float b){
  return (unsigned int)(unsigned short)f2b(a)
       | ((unsigned int)(unsigned short)f2b(b) << 16);
}
__device__ __forceinline__ float lo2f(unsigned int v){ return __uint_as_float(v << 16); }
__device__ __forceinline__ float hi2f(unsigned int v){ return __uint_as_float(v & 0xffff0000u); }

// ---------------------------------------------------------------------------
// Prep kernel: precM + ctab + precB + workspace/out zeroing riders (r10).
// precM stays here (r12 lesson: its 32768-thread parallelism is load-bearing).
__global__ __launch_bounds__(256) void k_prep(
    const float* __restrict__ A_log, const float* __restrict__ B_w,
    const float* __restrict__ Wmsg, const float* __restrict__ Wupd,
    float* __restrict__ c_tab, short* __restrict__ Bf, float* __restrict__ MT,
    int* __restrict__ cnt, float* __restrict__ out){
  int bid = blockIdx.x, tid = threadIdx.x;
  if (bid < PB_PRECM){                           // ---- precM: 2 hp per block
    int hp = bid*2 + (tid >> 7);                 // 0..255
    int e  = tid & 127;
    const float* w2 = Wupd + (size_t)hp*384 + 128;
    float acc = 0.f;
    for (int h1 = 0; h1 < HID; ++h1)
      acc += Wmsg[h1*EMBED + e] * w2[h1];
    MT[(size_t)hp*EMBED + e] = scrub(acc);
  } else if (bid < PB_CTAB){                     // ---- ctab (wave 0 only)
    if (tid < 64){
      int d = bid - PB_PRECM, lane = tid;        // d = 0..15
      float a0 = scrub(expf(-expf(A_log[(2*lane+0)*DSTATE + d])));
      float a1 = scrub(expf(-expf(A_log[(2*lane+1)*DSTATE + d])));
      float p0 = 1.f, p1 = 1.f;
      for (int k = 0; k < KTR; ++k){
        float s = p0 + p1;
        for (int off = 32; off; off >>= 1) s += __shfl_down(s, off);
        if (lane == 0) c_tab[k*DSTATE + d] = scrub(s * (1.0f/128.0f));
        p0 *= a0; p1 *= a1;
      }
    }
  } else if (bid < PB_PRECB){                    // ---- precB (256 slots)
    int idx = tid;
    int c = idx >> 6, lane = idx & 63;
    int n = lane & 15;
    int kb = c*32 + (lane >> 4)*8;
    short v[8];
    #pragma unroll
    for (int jj = 0; jj < 8; ++jj) v[jj] = f2b(B_w[(size_t)n*EMBED + kb + jj]);
    *(s16x8*)(Bf + (size_t)idx*8) = *(s16x8*)v;
  } else if (bid < PB_ZOUT){                     // ---- zero cnt/ovf_cnt/ovf
    int idx4 = (bid-PB_PRECB)*1024 + tid*4;      // 16B-aligned int offset
    if (idx4 < PB_ZNINT){
      uint4 z; z.x = z.y = z.z = z.w = 0u;
      *(uint4*)&cnt[idx4] = z;
    }
  } else {                                       // ---- zero out[160]
    if (tid < B_SZ*NCLS) out[tid] = 0.f;
  }
}

// ---------------------------------------------------------------------------
// Fused emb-cast + bproj(MFMA) + conv + ssm + LayerNorm.
//   r16: XCD-chunked swizzle on MAIN blocks (r15's proven mechanism applied
//   here). Tile k's 64-row halo = tile k-1's rows (same token positions ->
//   same emb rows). swz=(bid&7)*128+(bid>>3) gives each XCD a contiguous
//   tile run -> halo rows L2-warm. Pure reindexing: bit-identical.
__global__ __launch_bounds__(256) void k_ssm_fused(
    const int* __restrict__ tokens, const float* __restrict__ emb,
    const float* __restrict__ c_tab,
    const float* __restrict__ C_w, const float* __restrict__ D_skip,
    const float* __restrict__ ln_g, const float* __restrict__ ln_b,
    const short* __restrict__ Bf, const float* __restrict__ Wupd,
    const float* __restrict__ MT, unsigned int* __restrict__ h_out,
    short* __restrict__ Wcs, const int* __restrict__ edges,
    int* __restrict__ cnt, unsigned short* __restrict__ bucket,
    int* __restrict__ ovf_cnt, int* __restrict__ ovf){
  __shared__ unsigned int xsh[96][68];  // 26.1 KB x-tile (bf16 pairs)
  __shared__ float bsh[96][18];         // 6.75 KB; stride 18: 2-way (free)
  __shared__ float msh[32][18];         // 2.25 KB
  __shared__ float csh[KTR][DSTATE];    // 4 KB
  int bid = blockIdx.x, tid = threadIdx.x;

  if (bid >= SSM_PRECW){                // ---- bucket rider blocks
    int eid = (bid-SSM_PRECW)*256 + tid; // = B_SZ*NEDGE exactly
    int b2 = eid >> 13, i = eid & (NEDGE-1);
    const int* ei = edges + (size_t)b2*2*NEDGE;
    int s = ei[i]         & (SEQ-1);
    int d = ei[NEDGE + i] & (SEQ-1);
    int gdst = (b2 << 11) | d;
    int slot = atomicAdd(&cnt[gdst], 1);
    if (slot < BCAP) bucket[(size_t)gdst*BCAP + slot] = (unsigned short)s;
    else {
      int o = atomicAdd(ovf_cnt, 1);
      if (o < OVCAP) ovf[o] = ((b2 << 11) | s) | (gdst << 16);
    }
    return;
  }

  if (bid >= SSM_MAIN){                 // ---- precW rider blocks
    int idx = (bid-SSM_MAIN)*256 + tid; // 8192 fragment slots
    int c    = idx >> 10;
    int rem  = idx & 1023;
    int j    = rem >> 6;
    int lane = rem & 63;
    int n  = j*16 + (lane & 15);
    int kb = c*32 + (lane >> 4)*8;
    short v[8];
    #pragma unroll
    for (int jj = 0; jj < 8; ++jj){
      int k = kb + jj;
      float val = (k < 128) ? Wupd[(size_t)n*384 + k] : MT[(size_t)n*EMBED + (k-128)];
      v[jj] = f2b(val);
    }
    *(s16x8*)(Wcs + (size_t)idx*8) = *(s16x8*)v;
    return;
  }

  int swz = ((bid & 7) << 7) | (bid >> 3);  // bijective: 1024 % 8 == 0
  int b  = swz >> 6;                    // 64 blocks per batch
  int t0 = (swz & 63) * 32;
  int wv = tid >> 6, lane = tid & 63;
  int m = lane & 15, lg = lane >> 4;

  // ---- emb gather -> LDS x-tile: 96 rows (t0-64 .. t0+31), bit-identical
  {
    const int* tkb = tokens + b*SEQ;
    #pragma unroll
    for (int i = 0; i < 12; ++i){
      int gid = i*256 + tid;            // 3072 = 96 rows x 32 chunks
      int lr = gid >> 5, ch = gid & 31;
      int t = t0 - 64 + lr;
      uint2 o; o.x = 0u; o.y = 0u;
      if (t >= 0){
        int tok = tkb[t];
        tok = tok < 0 ? 0 : (tok >= VOCAB ? VOCAB-1 : tok);
        float4 v = *(const float4*)(emb + (size_t)tok*EMBED + ch*4);
        o.x = pack2(v.x, v.y); o.y = pack2(v.z, v.w);
      }
      *(uint2*)&xsh[lr][ch*2] = o;
    }
  }
  for (int i = tid; i < KTR*DSTATE; i += 256)
    csh[i >> 4][i & 15] = c_tab[i];

  // ---- C_w -> registers (32/lane): lane owns e0=lane*2, e0+1; contiguous
  int e0 = lane*2;
  float ct0[DSTATE], ct1[DSTATE];
  {
    const float4* c0 = (const float4*)(C_w + (size_t)e0*DSTATE);
    const float4* c1 = (const float4*)(C_w + (size_t)(e0+1)*DSTATE);
    #pragma unroll
    for (int i = 0; i < 4; ++i){
      float4 v0 = c0[i], v1 = c1[i];
      ct0[i*4+0]=v0.x; ct0[i*4+1]=v0.y; ct0[i*4+2]=v0.z; ct0[i*4+3]=v0.w;
      ct1[i*4+0]=v1.x; ct1[i*4+1]=v1.y; ct1[i*4+2]=v1.z; ct1[i*4+3]=v1.w;
    }
  }
  __syncthreads();

  // ---- bproj via MFMA: 6 tiles x 16 rows covering t0-64 .. t0+31 (from LDS)
  const s16x8* Bp = (const s16x8*)Bf;
  #pragma unroll
  for (int tt = 0; tt < 2; ++tt){
    int tile = wv*2 + tt;               // 0..7, use 0..5
    if (tile < 6){
      int trow = t0 - 64 + tile*16;
      f32x4 acc = (f32x4){0.f,0.f,0.f,0.f};
      if (trow >= 0){
        const short* xrow = (const short*)&xsh[tile*16 + m][0] + lg*8;
        #pragma unroll
        for (int c = 0; c < 4; ++c){
          s16x8 a = *(const s16x8*)(xrow + c*32);
          acc = __builtin_amdgcn_mfma_f32_16x16x32_bf16(a, Bp[c*64 + lane], acc, 0, 0, 0);
        }
      }
      // C/D: col = lane&15 (=d), row = lg*4 + r
      #pragma unroll
      for (int r = 0; r < 4; ++r)
        bsh[tile*16 + lg*4 + r][m] = scrub(acc[r]);
    }
  }
  __syncthreads();

  // ---- conv from LDS (taps in csh, uniform-address broadcast)
  {
    int d = tid & 15;
    #pragma unroll
    for (int it = 0; it < 2; ++it){
      int q = (tid + it*256) >> 4;      // 0..31
      int t = t0 + q;
      int base = 64 + q;
      int kmax = (t+1 < KTR) ? t+1 : KTR;
      float acc = 0.f;
      for (int k = 0; k < kmax; ++k) acc += csh[k][d] * bsh[base-k][d];
      msh[q][d] = scrub(acc);
    }
  }
  __syncthreads();

  // ---- ssm + LN: each wave 8 rows; x from LDS, C from registers
  float2 dsk = *(const float2*)&D_skip[e0];
  float2 lgv = *(const float2*)&ln_g[e0];
  float2 lbv = *(const float2*)&ln_b[e0];
  for (int q = wv*8; q < wv*8+8; ++q){
    int row = b*SEQ + t0 + q;
    unsigned int xp = xsh[64 + q][lane];
    float x0 = lo2f(xp), x1 = hi2f(xp);
    float y0 = dsk.x*x0, y1 = dsk.y*x1;
    #pragma unroll
    for (int d = 0; d < DSTATE; ++d){
      float md = msh[q][d];             // wave-uniform -> LDS broadcast
      y0 += md * ct0[d];
      y1 += md * ct1[d];
    }
    y0 = scrub(y0); y1 = scrub(y1);
    float s = y0+y1, s2 = y0*y0 + y1*y1;
    for (int off = 32; off; off >>= 1){ s += __shfl_down(s,off); s2 += __shfl_down(s2,off); }
    s = __shfl(s, 0); s2 = __shfl(s2, 0);
    float mu  = s * (1.f/EMBED);
    float var = s2 * (1.f/EMBED) - mu*mu;
    float inv = rsqrtf(fmaxf(var, 0.f) + LN_EPS);
    float o0 = scrub(lgv.x*(y0-mu)*inv + lbv.x);
    float o1 = scrub(lgv.y*(y1-mu)*inv + lbv.y);
    h_out[(size_t)row*(EMBED/2) + lane] = pack2(o0, o1);
  }
}

// ---------------------------------------------------------------------------
// Fused back half, r15 exact: r11 pipeline + XCD-aware block swizzle.
__global__ __launch_bounds__(256) void k_gupd(
    const short* __restrict__ h, const int* __restrict__ cnt,
    const unsigned short* __restrict__ bucket,
    const int* __restrict__ ovf_cnt, const int* __restrict__ ovf,
    const short* __restrict__ Wcs, const float* __restrict__ Wupd_b,
    const float* __restrict__ cls_w, const float* __restrict__ cls_b,
    float* __restrict__ out){
  __shared__ unsigned int gsh[16][68];   // padded g tile (b128-friendly)
  __shared__ float psum[HID];            // per-block pooled partials
  __shared__ float oacc[4][NCLS];        // per-wave class partials
  int tid = threadIdx.x;
  int wv = tid >> 6, lane = tid & 63;
  int bid0 = blockIdx.x;
  int swz  = ((bid0 & 7) << 8) | (bid0 >> 3);   // bijective: 2048 % 8 == 0
  int row0 = swz * 16;
  int b = row0 >> 11;                    // 16 | 2048: block is batch-pure
  int m = lane & 15, lg = lane >> 4;

  const unsigned int* hb  = (const unsigned int*)h + (size_t)b*SEQ*(EMBED/2);
  const unsigned int* h32 = (const unsigned int*)h;
  int hh = lane >> 5;                    // half-wave id 0/1
  int lw = lane & 31;                    // uint2 index within row

  // ---- phase 1: issue first 4-deep gather batch for both rows
  int rA = row0 + wv*4 + hh;
  int rB = row0 + wv*4 + 2 + hh;
  int nA = cnt[rA]; nA = nA > BCAP ? BCAP : nA;
  int nB = cnt[rB]; nB = nB > BCAP ? BCAP : nB;
  const unsigned short* bkA = bucket + (size_t)rA*BCAP;
  const unsigned short* bkB = bucket + (size_t)rB*BCAP;
  ushort4 sA = *(const ushort4*)bkA;     // BCAP=32 >= 4: always in-bounds
  ushort4 sB = *(const ushort4*)bkB;
  uint2 vA0 = *(const uint2*)&hb[(size_t)(0 < nA ? sA.x : 0)*(EMBED/2) + lw*2];
  uint2 vA1 = *(const uint2*)&hb[(size_t)(1 < nA ? sA.y : 0)*(EMBED/2) + lw*2];
  uint2 vA2 = *(const uint2*)&hb[(size_t)(2 < nA ? sA.z : 0)*(EMBED/2) + lw*2];
  uint2 vA3 = *(const uint2*)&hb[(size_t)(3 < nA ? sA.w : 0)*(EMBED/2) + lw*2];
  uint2 vB0 = *(const uint2*)&hb[(size_t)(0 < nB ? sB.x : 0)*(EMBED/2) + lw*2];
  uint2 vB1 = *(const uint2*)&hb[(size_t)(1 < nB ? sB.y : 0)*(EMBED/2) + lw*2];
  uint2 vB2 = *(const uint2*)&hb[(size_t)(2 < nB ? sB.z : 0)*(EMBED/2) + lw*2];
  uint2 vB3 = *(const uint2*)&hb[(size_t)(3 < nB ? sB.w : 0)*(EMBED/2) + lw*2];

  // ---- phase 2: h-part MFMAs (c=0..3) — independent of the gather
  const short* hrow = h + (size_t)(row0+m)*EMBED + lg*8;
  int j0 = wv*4;
  f32x4 acc[4];
  #pragma unroll
  for (int jj = 0; jj < 4; ++jj) acc[jj] = (f32x4){0.f,0.f,0.f,0.f};
  const s16x8* Bp = (const s16x8*)Wcs;
  #pragma unroll
  for (int c = 0; c < 4; ++c){
    s16x8 a = *(const s16x8*)(hrow + c*32);
    #pragma unroll
    for (int jj = 0; jj < 4; ++jj){
      s16x8 bfr = Bp[(c*16 + j0 + jj)*64 + lane];
      acc[jj] = __builtin_amdgcn_mfma_f32_16x16x32_bf16(a, bfr, acc[jj], 0, 0, 0);
    }
  }

  // ---- phase 3: finish gather (original t-order), pack to LDS, barrier
  int on = *ovf_cnt; on = on > OVCAP ? OVCAP : on;   // ~always 0
  {
    float ax0=0.f, ay0=0.f, ax1=0.f, ay1=0.f;
    if (0 < nA){ ax0 += lo2f(vA0.x); ay0 += hi2f(vA0.x); ax1 += lo2f(vA0.y); ay1 += hi2f(vA0.y); }
    if (1 < nA){ ax0 += lo2f(vA1.x); ay0 += hi2f(vA1.x); ax1 += lo2f(vA1.y); ay1 += hi2f(vA1.y); }
    if (2 < nA){ ax0 += lo2f(vA2.x); ay0 += hi2f(vA2.x); ax1 += lo2f(vA2.y); ay1 += hi2f(vA2.y); }
    if (3 < nA){ ax0 += lo2f(vA3.x); ay0 += hi2f(vA3.x); ax1 += lo2f(vA3.y); ay1 += hi2f(vA3.y); }
    for (int t = 4; t < nA; ++t){
      uint2 v = *(const uint2*)&hb[(size_t)bkA[t]*(EMBED/2) + lw*2];
      ax0 += lo2f(v.x); ay0 += hi2f(v.x); ax1 += lo2f(v.y); ay1 += hi2f(v.y);
    }
    for (int idx = 0; idx < on; ++idx){
      int pk = ovf[idx];
      if (((pk >> 16) & 0x7fff) == rA){
        uint2 v = *(const uint2*)&h32[(size_t)(pk & 0xffff)*(EMBED/2) + lw*2];
        ax0 += lo2f(v.x); ay0 += hi2f(v.x); ax1 += lo2f(v.y); ay1 += hi2f(v.y);
      }
    }
    uint2 o; o.x = pack2(scrub(ax0), scrub(ay0));
    o.y = pack2(scrub(ax1), scrub(ay1));
    *(uint2*)&gsh[rA - row0][lw*2] = o;
  }
  {
    float ax0=0.f, ay0=0.f, ax1=0.f, ay1=0.f;
    if (0 < nB){ ax0 += lo2f(vB0.x); ay0 += hi2f(vB0.x); ax1 += lo2f(vB0.y); ay1 += hi2f(vB0.y); }
    if (1 < nB){ ax0 += lo2f(vB1.x); ay0 += hi2f(vB1.x); ax1 += lo2f(vB1.y); ay1 += hi2f(vB1.y); }
    if (2 < nB){ ax0 += lo2f(vB2.x); ay0 += hi2f(vB2.x); ax1 += lo2f(vB2.y); ay1 += hi2f(vB2.y); }
    if (3 < nB){ ax0 += lo2f(vB3.x); ay0 += hi2f(vB3.x); ax1 += lo2f(vB3.y); ay1 += hi2f(vB3.y); }
    for (int t = 4; t < nB; ++t){
      uint2 v = *(const uint2*)&hb[(size_t)bkB[t]*(EMBED/2) + lw*2];
      ax0 += lo2f(v.x); ay0 += hi2f(v.x); ax1 += lo2f(v.y); ay1 += hi2f(v.y);
    }
    for (int idx = 0; idx < on; ++idx){
      int pk = ovf[idx];
      if (((pk >> 16) & 0x7fff) == rB){
        uint2 v = *(const uint2*)&h32[(size_t)(pk & 0xffff)*(EMBED/2) + lw*2];
        ax0 += lo2f(v.x); ay0 += hi2f(v.x); ax1 += lo2f(v.y); ay1 += hi2f(v.y);
      }
    }
    uint2 o; o.x = pack2(scrub(ax0), scrub(ay0));
    o.y = pack2(scrub(ax1), scrub(ay1));
    *(uint2*)&gsh[rB - row0][lw*2] = o;
  }
  __syncthreads();

  // ---- phase 4: g-part MFMAs (c=4..7) from LDS (same c-order as before)
  #pragma unroll
  for (int c = 4; c < 8; ++c){
    s16x8 a = *(const s16x8*)&gsh[m][(c-4)*16 + lg*4];
    #pragma unroll
    for (int jj = 0; jj < 4; ++jj){
      s16x8 bfr = Bp[(c*16 + j0 + jj)*64 + lane];
      acc[jj] = __builtin_amdgcn_mfma_f32_16x16x32_bf16(a, bfr, acc[jj], 0, 0, 0);
    }
  }

  // ---- relu + row-sum over this block's 16 rows -> psum[n] (disjoint n/wave)
  #pragma unroll
  for (int jj = 0; jj < 4; ++jj){
    int n = (j0 + jj)*16 + m;
    float bias = Wupd_b[n];
    float v = 0.f;
    #pragma unroll
    for (int r = 0; r < 4; ++r) v += fmaxf(acc[jj][r] + bias, 0.f);
    v += __shfl_down(v, 32);
    v += __shfl_down(v, 16);
    if (lane < 16) psum[n] = scrub(v);
  }
  __syncthreads();

  // ---- linear classifier epilogue: out[b][c] += (psum . cls_w[c]) / SEQ
  {
    float pn = psum[tid];                // tid = n, all 256 covered
    #pragma unroll
    for (int c = 0; c < NCLS; ++c){
      float t = pn * cls_w[c*HID + tid];
      for (int off = 32; off; off >>= 1) t += __shfl_down(t, off);
      if (lane == 0) oacc[wv][c] = t;
    }
    __syncthreads();
    if (tid < NCLS){
      float s = oacc[0][tid] + oacc[1][tid] + oacc[2][tid] + oacc[3][tid];
      atomicAdd(&out[b*NCLS + tid], scrub(s * (1.0f/SEQ)));
    }
    if ((swz & 127) == 0 && tid < NCLS)            // once per batch: bias
      atomicAdd(&out[b*NCLS + tid], cls_b[tid]);
  }
}

// ---------------------------------------------------------------------------
extern "C" void kernel_launch(void* const* d_in, const int* in_sizes, int n_in,
                              void* d_out, int out_size, void* d_ws, size_t ws_size,
                              hipStream_t stream) {
  const int*   tokens = (const int*)d_in[0];
  const int*   edges  = (const int*)d_in[2];
  const float* emb    = (const float*)d_in[3];
  const float* A_log  = (const float*)d_in[4];
  const float* B_w    = (const float*)d_in[5];
  const float* C_w    = (const float*)d_in[6];
  const float* D_skip = (const float*)d_in[7];
  const float* ln_g   = (const float*)d_in[8];
  const float* ln_b   = (const float*)d_in[9];
  const float* Wmsg   = (const float*)d_in[10];
  const float* Wupd   = (const float*)d_in[11];
  const float* Wupd_b = (const float*)d_in[12];
  const float* cls_w  = (const float*)d_in[13];
  const float* cls_b  = (const float*)d_in[14];
  float* out = (float*)d_out;

  // workspace layout (~10.4 MB)
  char* ws = (char*)d_ws;
  float* c_tab = (float*)ws;  ws += 16*1024;                 // 4 KB used
  float* MT    = (float*)ws;  ws += (size_t)HID*EMBED*4;     // 128 KB
  short* Wcs   = (short*)ws;  ws += (size_t)HID*HID*2;       // 128 KB
  short* Bf    = (short*)ws;  ws += 16*1024;                 // 4 KB used
  int*   cnt   = (int*)ws;    ws += (size_t)NROW*4;          // 128 KB
  int*   ovf_cnt = (int*)ws;  ws += 64;
  int*   ovf   = (int*)ws;    ws += OVCAP*4;                 // 4 KB
  unsigned short* bucket = (unsigned short*)ws; ws += (size_t)NROW*BCAP*2; // 2 MB
  short* h_bf  = (short*)ws;  ws += (size_t)NROW*EMBED*2;    // 8 MB

  // zeroing of cnt/ovf_cnt/ovf/out is done by k_prep rider blocks (r10)
  hipLaunchKernelGGL(k_prep, dim3(PB_TOTAL), dim3(256), 0, stream,
                     A_log, B_w, Wmsg, Wupd, c_tab, Bf, MT, cnt, out);
  hipLaunchKernelGGL(k_ssm_fused, dim3(SSM_TOTAL), dim3(256), 0, stream,
                     tokens, emb, c_tab, C_w, D_skip, ln_g, ln_b, Bf, Wupd, MT,
                     (unsigned int*)h_bf, Wcs, edges, cnt, bucket, ovf_cnt, ovf);
  hipLaunchKernelGGL(k_gupd, dim3(NROW/16), dim3(256), 0, stream,
                     h_bf, cnt, bucket, ovf_cnt, ovf, Wcs, Wupd_b,
                     cls_w, cls_b, out);
}

// Round 17
// 164.362 us; speedup vs baseline: 1.0826x; 1.0002x over previous
//
#include <hip/hip_runtime.h>

#define B_SZ   16
#define SEQ    2048
#define VOCAB  50257
#define EMBED  128
#define DSTATE 16
#define HID    256
#define NCLS   10
#define NEDGE  8192
#define KTR    64          // scan truncation: A<=0.55 -> A^64 < 2e-17
#define LN_EPS 1e-5f
#define NROW   (B_SZ*SEQ)  // 32768
#define BCAP   32          // bucket capacity per dst (Poisson lambda=4)
#define OVCAP  1024        // overflow fallback capacity

// k_prep phase block ranges
#define PB_PRECM  128                   // 256 hp, 2 per block
#define PB_CTAB   (PB_PRECM + 16)       // 16 d
#define PB_PRECB  (PB_CTAB + 1)         // +1 precB          = 145
#define PB_ZNINT  33808                 // cnt(32768)+ovf_cnt(16)+ovf(1024)
#define PB_ZBLK   34                    // ceil(33808/1024)
#define PB_ZOUT   (PB_PRECB + PB_ZBLK)  // 179: zero out[160]
#define PB_TOTAL  (PB_ZOUT + 1)         // 180

// k_ssm_fused block ranges
#define SSM_MAIN  1024                  // 16 batches x 64 tiles of 32 rows
#define SSM_PRECW (SSM_MAIN + 32)       // 1056
#define SSM_TOTAL (SSM_PRECW + 512)     // 1568 (bucket riders)

typedef float  f32x4 __attribute__((ext_vector_type(4)));
typedef short  s16x8 __attribute__((ext_vector_type(8)));

__device__ __forceinline__ float scrub(float x){
  return (x == x && fabsf(x) < 1e30f) ? x : 0.f;
}
// fp32 -> bf16 bits, round-to-nearest-even
__device__ __forceinline__ short f2b(float f){
  unsigned int u = __float_as_uint(f);
  unsigned int r = (u + 0x7fffu + ((u >> 16) & 1u)) >> 16;
  return (short)r;
}
__device__ __forceinline__ unsigned int pack2(float a, float b){
  return (unsigned int)(unsigned short)f2b(a)
       | ((unsigned int)(unsigned short)f2b(b) << 16);
}
__device__ __forceinline__ float lo2f(unsigned int v){ return __uint_as_float(v << 16); }
__device__ __forceinline__ float hi2f(unsigned int v){ return __uint_as_float(v & 0xffff0000u); }

// ---------------------------------------------------------------------------
// Prep kernel: precM + ctab + precB + workspace/out zeroing riders (r10).
// precM stays here (r12 lesson: its 32768-thread parallelism is load-bearing).
__global__ __launch_bounds__(256) void k_prep(
    const float* __restrict__ A_log, const float* __restrict__ B_w,
    const float* __restrict__ Wmsg, const float* __restrict__ Wupd,
    float* __restrict__ c_tab, short* __restrict__ Bf, float* __restrict__ MT,
    int* __restrict__ cnt, float* __restrict__ out){
  int bid = blockIdx.x, tid = threadIdx.x;
  if (bid < PB_PRECM){                           // ---- precM: 2 hp per block
    int hp = bid*2 + (tid >> 7);                 // 0..255
    int e  = tid & 127;
    const float* w2 = Wupd + (size_t)hp*384 + 128;
    float acc = 0.f;
    for (int h1 = 0; h1 < HID; ++h1)
      acc += Wmsg[h1*EMBED + e] * w2[h1];
    MT[(size_t)hp*EMBED + e] = scrub(acc);
  } else if (bid < PB_CTAB){                     // ---- ctab (wave 0 only)
    if (tid < 64){
      int d = bid - PB_PRECM, lane = tid;        // d = 0..15
      float a0 = scrub(expf(-expf(A_log[(2*lane+0)*DSTATE + d])));
      float a1 = scrub(expf(-expf(A_log[(2*lane+1)*DSTATE + d])));
      float p0 = 1.f, p1 = 1.f;
      for (int k = 0; k < KTR; ++k){
        float s = p0 + p1;
        for (int off = 32; off; off >>= 1) s += __shfl_down(s, off);
        if (lane == 0) c_tab[k*DSTATE + d] = scrub(s * (1.0f/128.0f));
        p0 *= a0; p1 *= a1;
      }
    }
  } else if (bid < PB_PRECB){                    // ---- precB (256 slots)
    int idx = tid;
    int c = idx >> 6, lane = idx & 63;
    int n = lane & 15;
    int kb = c*32 + (lane >> 4)*8;
    short v[8];
    #pragma unroll
    for (int jj = 0; jj < 8; ++jj) v[jj] = f2b(B_w[(size_t)n*EMBED + kb + jj]);
    *(s16x8*)(Bf + (size_t)idx*8) = *(s16x8*)v;
  } else if (bid < PB_ZOUT){                     // ---- zero cnt/ovf_cnt/ovf
    int idx4 = (bid-PB_PRECB)*1024 + tid*4;      // 16B-aligned int offset
    if (idx4 < PB_ZNINT){
      uint4 z; z.x = z.y = z.z = z.w = 0u;
      *(uint4*)&cnt[idx4] = z;
    }
  } else {                                       // ---- zero out[160]
    if (tid < B_SZ*NCLS) out[tid] = 0.f;
  }
}

// ---------------------------------------------------------------------------
// Fused emb-cast + bproj(MFMA) + conv + ssm + LayerNorm.
//   r16: XCD-chunked swizzle on main blocks (halo rows L2-warm).
//   r17: Bf B-fragments hoisted to registers BEFORE the gather — their L2
//   latency hides under the 12-iteration emb gather (values/order unchanged).
__global__ __launch_bounds__(256) void k_ssm_fused(
    const int* __restrict__ tokens, const float* __restrict__ emb,
    const float* __restrict__ c_tab,
    const float* __restrict__ C_w, const float* __restrict__ D_skip,
    const float* __restrict__ ln_g, const float* __restrict__ ln_b,
    const short* __restrict__ Bf, const float* __restrict__ Wupd,
    const float* __restrict__ MT, unsigned int* __restrict__ h_out,
    short* __restrict__ Wcs, const int* __restrict__ edges,
    int* __restrict__ cnt, unsigned short* __restrict__ bucket,
    int* __restrict__ ovf_cnt, int* __restrict__ ovf){
  __shared__ unsigned int xsh[96][68];  // 26.1 KB x-tile (bf16 pairs)
  __shared__ float bsh[96][18];         // 6.75 KB; stride 18: 2-way (free)
  __shared__ float msh[32][18];         // 2.25 KB
  __shared__ float csh[KTR][DSTATE];    // 4 KB
  int bid = blockIdx.x, tid = threadIdx.x;

  if (bid >= SSM_PRECW){                // ---- bucket rider blocks
    int eid = (bid-SSM_PRECW)*256 + tid; // = B_SZ*NEDGE exactly
    int b2 = eid >> 13, i = eid & (NEDGE-1);
    const int* ei = edges + (size_t)b2*2*NEDGE;
    int s = ei[i]         & (SEQ-1);
    int d = ei[NEDGE + i] & (SEQ-1);
    int gdst = (b2 << 11) | d;
    int slot = atomicAdd(&cnt[gdst], 1);
    if (slot < BCAP) bucket[(size_t)gdst*BCAP + slot] = (unsigned short)s;
    else {
      int o = atomicAdd(ovf_cnt, 1);
      if (o < OVCAP) ovf[o] = ((b2 << 11) | s) | (gdst << 16);
    }
    return;
  }

  if (bid >= SSM_MAIN){                 // ---- precW rider blocks
    int idx = (bid-SSM_MAIN)*256 + tid; // 8192 fragment slots
    int c    = idx >> 10;
    int rem  = idx & 1023;
    int j    = rem >> 6;
    int lane = rem & 63;
    int n  = j*16 + (lane & 15);
    int kb = c*32 + (lane >> 4)*8;
    short v[8];
    #pragma unroll
    for (int jj = 0; jj < 8; ++jj){
      int k = kb + jj;
      float val = (k < 128) ? Wupd[(size_t)n*384 + k] : MT[(size_t)n*EMBED + (k-128)];
      v[jj] = f2b(val);
    }
    *(s16x8*)(Wcs + (size_t)idx*8) = *(s16x8*)v;
    return;
  }

  int swz = ((bid & 7) << 7) | (bid >> 3);  // bijective: 1024 % 8 == 0
  int b  = swz >> 6;                    // 64 blocks per batch
  int t0 = (swz & 63) * 32;
  int wv = tid >> 6, lane = tid & 63;
  int m = lane & 15, lg = lane >> 4;

  // ---- r17: issue Bf fragment loads FIRST (consumed after the barrier;
  // latency hides under the emb gather below). Same values as before.
  const s16x8* Bp = (const s16x8*)Bf;
  s16x8 bfr[4];
  #pragma unroll
  for (int c = 0; c < 4; ++c) bfr[c] = Bp[c*64 + lane];

  // ---- emb gather -> LDS x-tile: 96 rows (t0-64 .. t0+31), bit-identical
  {
    const int* tkb = tokens + b*SEQ;
    #pragma unroll
    for (int i = 0; i < 12; ++i){
      int gid = i*256 + tid;            // 3072 = 96 rows x 32 chunks
      int lr = gid >> 5, ch = gid & 31;
      int t = t0 - 64 + lr;
      uint2 o; o.x = 0u; o.y = 0u;
      if (t >= 0){
        int tok = tkb[t];
        tok = tok < 0 ? 0 : (tok >= VOCAB ? VOCAB-1 : tok);
        float4 v = *(const float4*)(emb + (size_t)tok*EMBED + ch*4);
        o.x = pack2(v.x, v.y); o.y = pack2(v.z, v.w);
      }
      *(uint2*)&xsh[lr][ch*2] = o;
    }
  }
  for (int i = tid; i < KTR*DSTATE; i += 256)
    csh[i >> 4][i & 15] = c_tab[i];

  // ---- C_w -> registers (32/lane): lane owns e0=lane*2, e0+1; contiguous
  int e0 = lane*2;
  float ct0[DSTATE], ct1[DSTATE];
  {
    const float4* c0 = (const float4*)(C_w + (size_t)e0*DSTATE);
    const float4* c1 = (const float4*)(C_w + (size_t)(e0+1)*DSTATE);
    #pragma unroll
    for (int i = 0; i < 4; ++i){
      float4 v0 = c0[i], v1 = c1[i];
      ct0[i*4+0]=v0.x; ct0[i*4+1]=v0.y; ct0[i*4+2]=v0.z; ct0[i*4+3]=v0.w;
      ct1[i*4+0]=v1.x; ct1[i*4+1]=v1.y; ct1[i*4+2]=v1.z; ct1[i*4+3]=v1.w;
    }
  }
  __syncthreads();

  // ---- bproj via MFMA: 6 tiles x 16 rows covering t0-64 .. t0+31 (from LDS)
  #pragma unroll
  for (int tt = 0; tt < 2; ++tt){
    int tile = wv*2 + tt;               // 0..7, use 0..5
    if (tile < 6){
      int trow = t0 - 64 + tile*16;
      f32x4 acc = (f32x4){0.f,0.f,0.f,0.f};
      if (trow >= 0){
        const short* xrow = (const short*)&xsh[tile*16 + m][0] + lg*8;
        #pragma unroll
        for (int c = 0; c < 4; ++c){
          s16x8 a = *(const s16x8*)(xrow + c*32);
          acc = __builtin_amdgcn_mfma_f32_16x16x32_bf16(a, bfr[c], acc, 0, 0, 0);
        }
      }
      // C/D: col = lane&15 (=d), row = lg*4 + r
      #pragma unroll
      for (int r = 0; r < 4; ++r)
        bsh[tile*16 + lg*4 + r][m] = scrub(acc[r]);
    }
  }
  __syncthreads();

  // ---- conv from LDS (taps in csh, uniform-address broadcast)
  {
    int d = tid & 15;
    #pragma unroll
    for (int it = 0; it < 2; ++it){
      int q = (tid + it*256) >> 4;      // 0..31
      int t = t0 + q;
      int base = 64 + q;
      int kmax = (t+1 < KTR) ? t+1 : KTR;
      float acc = 0.f;
      for (int k = 0; k < kmax; ++k) acc += csh[k][d] * bsh[base-k][d];
      msh[q][d] = scrub(acc);
    }
  }
  __syncthreads();

  // ---- ssm + LN: each wave 8 rows; x from LDS, C from registers
  float2 dsk = *(const float2*)&D_skip[e0];
  float2 lgv = *(const float2*)&ln_g[e0];
  float2 lbv = *(const float2*)&ln_b[e0];
  for (int q = wv*8; q < wv*8+8; ++q){
    int row = b*SEQ + t0 + q;
    unsigned int xp = xsh[64 + q][lane];
    float x0 = lo2f(xp), x1 = hi2f(xp);
    float y0 = dsk.x*x0, y1 = dsk.y*x1;
    #pragma unroll
    for (int d = 0; d < DSTATE; ++d){
      float md = msh[q][d];             // wave-uniform -> LDS broadcast
      y0 += md * ct0[d];
      y1 += md * ct1[d];
    }
    y0 = scrub(y0); y1 = scrub(y1);
    float s = y0+y1, s2 = y0*y0 + y1*y1;
    for (int off = 32; off; off >>= 1){ s += __shfl_down(s,off); s2 += __shfl_down(s2,off); }
    s = __shfl(s, 0); s2 = __shfl(s2, 0);
    float mu  = s * (1.f/EMBED);
    float var = s2 * (1.f/EMBED) - mu*mu;
    float inv = rsqrtf(fmaxf(var, 0.f) + LN_EPS);
    float o0 = scrub(lgv.x*(y0-mu)*inv + lbv.x);
    float o1 = scrub(lgv.y*(y1-mu)*inv + lbv.y);
    h_out[(size_t)row*(EMBED/2) + lane] = pack2(o0, o1);
  }
}

// ---------------------------------------------------------------------------
// Fused back half: r11 pipeline + r15 XCD swizzle + r17 batched tail.
//   Poisson(4) => ~37% of rows have n>4; the old serial tail was 1-deep
//   dependent loads. Batch it 4-deep (r7 pattern); adds stay in t-order.
__global__ __launch_bounds__(256) void k_gupd(
    const short* __restrict__ h, const int* __restrict__ cnt,
    const unsigned short* __restrict__ bucket,
    const int* __restrict__ ovf_cnt, const int* __restrict__ ovf,
    const short* __restrict__ Wcs, const float* __restrict__ Wupd_b,
    const float* __restrict__ cls_w, const float* __restrict__ cls_b,
    float* __restrict__ out){
  __shared__ unsigned int gsh[16][68];   // padded g tile (b128-friendly)
  __shared__ float psum[HID];            // per-block pooled partials
  __shared__ float oacc[4][NCLS];        // per-wave class partials
  int tid = threadIdx.x;
  int wv = tid >> 6, lane = tid & 63;
  int bid0 = blockIdx.x;
  int swz  = ((bid0 & 7) << 8) | (bid0 >> 3);   // bijective: 2048 % 8 == 0
  int row0 = swz * 16;
  int b = row0 >> 11;                    // 16 | 2048: block is batch-pure
  int m = lane & 15, lg = lane >> 4;

  const unsigned int* hb  = (const unsigned int*)h + (size_t)b*SEQ*(EMBED/2);
  const unsigned int* h32 = (const unsigned int*)h;
  int hh = lane >> 5;                    // half-wave id 0/1
  int lw = lane & 31;                    // uint2 index within row

  // ---- phase 1: issue first 4-deep gather batch for both rows
  int rA = row0 + wv*4 + hh;
  int rB = row0 + wv*4 + 2 + hh;
  int nA = cnt[rA]; nA = nA > BCAP ? BCAP : nA;
  int nB = cnt[rB]; nB = nB > BCAP ? BCAP : nB;
  const unsigned short* bkA = bucket + (size_t)rA*BCAP;
  const unsigned short* bkB = bucket + (size_t)rB*BCAP;
  ushort4 sA = *(const ushort4*)bkA;     // BCAP=32 >= 4: always in-bounds
  ushort4 sB = *(const ushort4*)bkB;
  uint2 vA0 = *(const uint2*)&hb[(size_t)(0 < nA ? sA.x : 0)*(EMBED/2) + lw*2];
  uint2 vA1 = *(const uint2*)&hb[(size_t)(1 < nA ? sA.y : 0)*(EMBED/2) + lw*2];
  uint2 vA2 = *(const uint2*)&hb[(size_t)(2 < nA ? sA.z : 0)*(EMBED/2) + lw*2];
  uint2 vA3 = *(const uint2*)&hb[(size_t)(3 < nA ? sA.w : 0)*(EMBED/2) + lw*2];
  uint2 vB0 = *(const uint2*)&hb[(size_t)(0 < nB ? sB.x : 0)*(EMBED/2) + lw*2];
  uint2 vB1 = *(const uint2*)&hb[(size_t)(1 < nB ? sB.y : 0)*(EMBED/2) + lw*2];
  uint2 vB2 = *(const uint2*)&hb[(size_t)(2 < nB ? sB.z : 0)*(EMBED/2) + lw*2];
  uint2 vB3 = *(const uint2*)&hb[(size_t)(3 < nB ? sB.w : 0)*(EMBED/2) + lw*2];

  // ---- phase 2: h-part MFMAs (c=0..3) — independent of the gather
  const short* hrow = h + (size_t)(row0+m)*EMBED + lg*8;
  int j0 = wv*4;
  f32x4 acc[4];
  #pragma unroll
  for (int jj = 0; jj < 4; ++jj) acc[jj] = (f32x4){0.f,0.f,0.f,0.f};
  const s16x8* Bp = (const s16x8*)Wcs;
  #pragma unroll
  for (int c = 0; c < 4; ++c){
    s16x8 a = *(const s16x8*)(hrow + c*32);
    #pragma unroll
    for (int jj = 0; jj < 4; ++jj){
      s16x8 bfr = Bp[(c*16 + j0 + jj)*64 + lane];
      acc[jj] = __builtin_amdgcn_mfma_f32_16x16x32_bf16(a, bfr, acc[jj], 0, 0, 0);
    }
  }

  // ---- phase 3: finish gather (original t-order), pack to LDS, barrier
  int on = *ovf_cnt; on = on > OVCAP ? OVCAP : on;   // ~always 0
  {
    float ax0=0.f, ay0=0.f, ax1=0.f, ay1=0.f;
    if (0 < nA){ ax0 += lo2f(vA0.x); ay0 += hi2f(vA0.x); ax1 += lo2f(vA0.y); ay1 += hi2f(vA0.y); }
    if (1 < nA){ ax0 += lo2f(vA1.x); ay0 += hi2f(vA1.x); ax1 += lo2f(vA1.y); ay1 += hi2f(vA1.y); }
    if (2 < nA){ ax0 += lo2f(vA2.x); ay0 += hi2f(vA2.x); ax1 += lo2f(vA2.y); ay1 += hi2f(vA2.y); }
    if (3 < nA){ ax0 += lo2f(vA3.x); ay0 += hi2f(vA3.x); ax1 += lo2f(vA3.y); ay1 += hi2f(vA3.y); }
    int t = 4;
    for (; t + 4 <= nA; t += 4){         // r17: 4-deep batched tail
      ushort4 s4 = *(const ushort4*)(bkA + t);
      uint2 w0 = *(const uint2*)&hb[(size_t)s4.x*(EMBED/2) + lw*2];
      uint2 w1 = *(const uint2*)&hb[(size_t)s4.y*(EMBED/2) + lw*2];
      uint2 w2 = *(const uint2*)&hb[(size_t)s4.z*(EMBED/2) + lw*2];
      uint2 w3 = *(const uint2*)&hb[(size_t)s4.w*(EMBED/2) + lw*2];
      ax0 += lo2f(w0.x); ay0 += hi2f(w0.x); ax1 += lo2f(w0.y); ay1 += hi2f(w0.y);
      ax0 += lo2f(w1.x); ay0 += hi2f(w1.x); ax1 += lo2f(w1.y); ay1 += hi2f(w1.y);
      ax0 += lo2f(w2.x); ay0 += hi2f(w2.x); ax1 += lo2f(w2.y); ay1 += hi2f(w2.y);
      ax0 += lo2f(w3.x); ay0 += hi2f(w3.x); ax1 += lo2f(w3.y); ay1 += hi2f(w3.y);
    }
    for (; t < nA; ++t){
      uint2 v = *(const uint2*)&hb[(size_t)bkA[t]*(EMBED/2) + lw*2];
      ax0 += lo2f(v.x); ay0 += hi2f(v.x); ax1 += lo2f(v.y); ay1 += hi2f(v.y);
    }
    for (int idx = 0; idx < on; ++idx){
      int pk = ovf[idx];
      if (((pk >> 16) & 0x7fff) == rA){
        uint2 v = *(const uint2*)&h32[(size_t)(pk & 0xffff)*(EMBED/2) + lw*2];
        ax0 += lo2f(v.x); ay0 += hi2f(v.x); ax1 += lo2f(v.y); ay1 += hi2f(v.y);
      }
    }
    uint2 o; o.x = pack2(scrub(ax0), scrub(ay0));
    o.y = pack2(scrub(ax1), scrub(ay1));
    *(uint2*)&gsh[rA - row0][lw*2] = o;
  }
  {
    float ax0=0.f, ay0=0.f, ax1=0.f, ay1=0.f;
    if (0 < nB){ ax0 += lo2f(vB0.x); ay0 += hi2f(vB0.x); ax1 += lo2f(vB0.y); ay1 += hi2f(vB0.y); }
    if (1 < nB){ ax0 += lo2f(vB1.x); ay0 += hi2f(vB1.x); ax1 += lo2f(vB1.y); ay1 += hi2f(vB1.y); }
    if (2 < nB){ ax0 += lo2f(vB2.x); ay0 += hi2f(vB2.x); ax1 += lo2f(vB2.y); ay1 += hi2f(vB2.y); }
    if (3 < nB){ ax0 += lo2f(vB3.x); ay0 += hi2f(vB3.x); ax1 += lo2f(vB3.y); ay1 += hi2f(vB3.y); }
    int t = 4;
    for (; t + 4 <= nB; t += 4){         // r17: 4-deep batched tail
      ushort4 s4 = *(const ushort4*)(bkB + t);
      uint2 w0 = *(const uint2*)&hb[(size_t)s4.x*(EMBED/2) + lw*2];
      uint2 w1 = *(const uint2*)&hb[(size_t)s4.y*(EMBED/2) + lw*2];
      uint2 w2 = *(const uint2*)&hb[(size_t)s4.z*(EMBED/2) + lw*2];
      uint2 w3 = *(const uint2*)&hb[(size_t)s4.w*(EMBED/2) + lw*2];
      ax0 += lo2f(w0.x); ay0 += hi2f(w0.x); ax1 += lo2f(w0.y); ay1 += hi2f(w0.y);
      ax0 += lo2f(w1.x); ay0 += hi2f(w1.x); ax1 += lo2f(w1.y); ay1 += hi2f(w1.y);
      ax0 += lo2f(w2.x); ay0 += hi2f(w2.x); ax1 += lo2f(w2.y); ay1 += hi2f(w2.y);
      ax0 += lo2f(w3.x); ay0 += hi2f(w3.x); ax1 += lo2f(w3.y); ay1 += hi2f(w3.y);
    }
    for (; t < nB; ++t){
      uint2 v = *(const uint2*)&hb[(size_t)bkB[t]*(EMBED/2) + lw*2];
      ax0 += lo2f(v.x); ay0 += hi2f(v.x); ax1 += lo2f(v.y); ay1 += hi2f(v.y);
    }
    for (int idx = 0; idx < on; ++idx){
      int pk = ovf[idx];
      if (((pk >> 16) & 0x7fff) == rB){
        uint2 v = *(const uint2*)&h32[(size_t)(pk & 0xffff)*(EMBED/2) + lw*2];
        ax0 += lo2f(v.x); ay0 += hi2f(v.x); ax1 += lo2f(v.y); ay1 += hi2f(v.y);
      }
    }
    uint2 o; o.x = pack2(scrub(ax0), scrub(ay0));
    o.y = pack2(scrub(ax1), scrub(ay1));
    *(uint2*)&gsh[rB - row0][lw*2] = o;
  }
  __syncthreads();

  // ---- phase 4: g-part MFMAs (c=4..7) from LDS (same c-order as before)
  #pragma unroll
  for (int c = 4; c < 8; ++c){
    s16x8 a = *(const s16x8*)&gsh[m][(c-4)*16 + lg*4];
    #pragma unroll
    for (int jj = 0; jj < 4; ++jj){
      s16x8 bfr = Bp[(c*16 + j0 + jj)*64 + lane];
      acc[jj] = __builtin_amdgcn_mfma_f32_16x16x32_bf16(a, bfr, acc[jj], 0, 0, 0);
    }
  }

  // ---- relu + row-sum over this block's 16 rows -> psum[n] (disjoint n/wave)
  #pragma unroll
  for (int jj = 0; jj < 4; ++jj){
    int n = (j0 + jj)*16 + m;
    float bias = Wupd_b[n];
    float v = 0.f;
    #pragma unroll
    for (int r = 0; r < 4; ++r) v += fmaxf(acc[jj][r] + bias, 0.f);
    v += __shfl_down(v, 32);
    v += __shfl_down(v, 16);
    if (lane < 16) psum[n] = scrub(v);
  }
  __syncthreads();

  // ---- linear classifier epilogue: out[b][c] += (psum . cls_w[c]) / SEQ
  {
    float pn = psum[tid];                // tid = n, all 256 covered
    #pragma unroll
    for (int c = 0; c < NCLS; ++c){
      float t = pn * cls_w[c*HID + tid];
      for (int off = 32; off; off >>= 1) t += __shfl_down(t, off);
      if (lane == 0) oacc[wv][c] = t;
    }
    __syncthreads();
    if (tid < NCLS){
      float s = oacc[0][tid] + oacc[1][tid] + oacc[2][tid] + oacc[3][tid];
      atomicAdd(&out[b*NCLS + tid], scrub(s * (1.0f/SEQ)));
    }
    if ((swz & 127) == 0 && tid < NCLS)            // once per batch: bias
      atomicAdd(&out[b*NCLS + tid], cls_b[tid]);
  }
}

// ---------------------------------------------------------------------------
extern "C" void kernel_launch(void* const* d_in, const int* in_sizes, int n_in,
                              void* d_out, int out_size, void* d_ws, size_t ws_size,
                              hipStream_t stream) {
  const int*   tokens = (const int*)d_in[0];
  const int*   edges  = (const int*)d_in[2];
  const float* emb    = (const float*)d_in[3];
  const float* A_log  = (const float*)d_in[4];
  const float* B_w    = (const float*)d_in[5];
  const float* C_w    = (const float*)d_in[6];
  const float* D_skip = (const float*)d_in[7];
  const float* ln_g   = (const float*)d_in[8];
  const float* ln_b   = (const float*)d_in[9];
  const float* Wmsg   = (const float*)d_in[10];
  const float* Wupd   = (const float*)d_in[11];
  const float* Wupd_b = (const float*)d_in[12];
  const float* cls_w  = (const float*)d_in[13];
  const float* cls_b  = (const float*)d_in[14];
  float* out = (float*)d_out;

  // workspace layout (~10.4 MB)
  char* ws = (char*)d_ws;
  float* c_tab = (float*)ws;  ws += 16*1024;                 // 4 KB used
  float* MT    = (float*)ws;  ws += (size_t)HID*EMBED*4;     // 128 KB
  short* Wcs   = (short*)ws;  ws += (size_t)HID*HID*2;       // 128 KB
  short* Bf    = (short*)ws;  ws += 16*1024;                 // 4 KB used
  int*   cnt   = (int*)ws;    ws += (size_t)NROW*4;          // 128 KB
  int*   ovf_cnt = (int*)ws;  ws += 64;
  int*   ovf   = (int*)ws;    ws += OVCAP*4;                 // 4 KB
  unsigned short* bucket = (unsigned short*)ws; ws += (size_t)NROW*BCAP*2; // 2 MB
  short* h_bf  = (short*)ws;  ws += (size_t)NROW*EMBED*2;    // 8 MB

  // zeroing of cnt/ovf_cnt/ovf/out is done by k_prep rider blocks (r10)
  hipLaunchKernelGGL(k_prep, dim3(PB_TOTAL), dim3(256), 0, stream,
                     A_log, B_w, Wmsg, Wupd, c_tab, Bf, MT, cnt, out);
  hipLaunchKernelGGL(k_ssm_fused, dim3(SSM_TOTAL), dim3(256), 0, stream,
                     tokens, emb, c_tab, C_w, D_skip, ln_g, ln_b, Bf, Wupd, MT,
                     (unsigned int*)h_bf, Wcs, edges, cnt, bucket, ovf_cnt, ovf);
  hipLaunchKernelGGL(k_gupd, dim3(NROW/16), dim3(256), 0, stream,
                     h_bf, cnt, bucket, ovf_cnt, ovf, Wcs, Wupd_b,
                     cls_w, cls_b, out);
}